// Round 1
// baseline (4326.868 us; speedup 1.0000x reference)
//
#include <hip/hip_runtime.h>
#include <hip/hip_bf16.h>
#include <math.h>

#define N_NODES 100000
#define N_EDGES 1600000
#define N_GRAPHS 64
#define IN_DIM 128
#define HID 256
#define NCLS 16

#define SCAN_CHUNK 1024
#define SCAN_BLOCKS ((N_NODES + SCAN_CHUNK - 1) / SCAN_CHUNK)  // 98

// ---------------- K1: degree count (int atomics, cheap) ----------------
__global__ void k_degrees(const int* __restrict__ src, const int* __restrict__ dst,
                          int* __restrict__ deg_out, int* __restrict__ deg_in) {
  int i = blockIdx.x * blockDim.x + threadIdx.x;
  int stride = gridDim.x * blockDim.x;
  for (; i < N_EDGES; i += stride) {
    atomicAdd(&deg_out[src[i]], 1);
    atomicAdd(&deg_in[dst[i]], 1);
  }
}

// ---------------- K2: per-chunk exclusive scan of deg_in ----------------
__global__ void k_scan1(const int* __restrict__ deg_in, int* __restrict__ offs,
                        int* __restrict__ blockSums) {
  __shared__ int sdata[256];
  int b = blockIdx.x, t = threadIdx.x;
  int base = b * SCAN_CHUNK + t * 4;
  int v[4];
#pragma unroll
  for (int j = 0; j < 4; j++) {
    int idx = base + j;
    v[j] = (idx < N_NODES) ? deg_in[idx] : 0;
  }
  int tsum = v[0] + v[1] + v[2] + v[3];
  sdata[t] = tsum;
  __syncthreads();
  for (int off = 1; off < 256; off <<= 1) {
    int x = sdata[t];
    int y = (t >= off) ? sdata[t - off] : 0;
    __syncthreads();
    sdata[t] = x + y;
    __syncthreads();
  }
  int run = sdata[t] - tsum;  // exclusive prefix of this thread's chunk
#pragma unroll
  for (int j = 0; j < 4; j++) {
    int idx = base + j;
    if (idx < N_NODES) offs[idx] = run;
    run += v[j];
  }
  if (t == 255) blockSums[b] = sdata[255];
}

// ---------------- K3: scan the 98 block sums (one block) ----------------
__global__ void k_scan2(int* __restrict__ blockSums) {
  __shared__ int sdata[128];
  int t = threadIdx.x;
  int v = (t < SCAN_BLOCKS) ? blockSums[t] : 0;
  sdata[t] = v;
  __syncthreads();
  for (int off = 1; off < 128; off <<= 1) {
    int x = sdata[t];
    int y = (t >= off) ? sdata[t - off] : 0;
    __syncthreads();
    sdata[t] = x + y;
    __syncthreads();
  }
  if (t < SCAN_BLOCKS) blockSums[t] = sdata[t] - v;  // exclusive
}

// ------- K4: finalize offsets, init cursors, compute D^-1/2 norms -------
__global__ void k_finalize(const int* __restrict__ deg_out, const int* __restrict__ deg_in,
                           const int* __restrict__ blockSums,
                           int* __restrict__ offs, int* __restrict__ cursor,
                           float* __restrict__ norm_src, float* __restrict__ norm_dst) {
  int i = blockIdx.x * blockDim.x + threadIdx.x;
  if (i >= N_NODES) return;
  int o = offs[i] + blockSums[i / SCAN_CHUNK];
  offs[i] = o;
  cursor[i] = o;
  norm_src[i] = rsqrtf((float)deg_out[i] + 1.0f);  // self-loop adds +1
  norm_dst[i] = rsqrtf((float)deg_in[i] + 1.0f);
}

// ---------------- K5: scatter edges into CSR buckets by dst ----------------
__global__ void k_scatter(const int* __restrict__ src, const int* __restrict__ dst,
                          int* __restrict__ cursor, int* __restrict__ edge_src) {
  int i = blockIdx.x * blockDim.x + threadIdx.x;
  int stride = gridDim.x * blockDim.x;
  for (; i < N_EDGES; i += stride) {
    int d = dst[i];
    int pos = atomicAdd(&cursor[d], 1);
    edge_src[pos] = src[i];
  }
}

// --------- K6: pull-aggregate. One wave per node, float2 per lane ---------
// agg[v] = norm_dst[v] * ( x[v]*norm_src[v] + sum_{u->v} x[u]*norm_src[u] )
__global__ __launch_bounds__(256) void k_aggregate(
    const float* __restrict__ x, const int* __restrict__ edge_src,
    const int* __restrict__ offs, const int* __restrict__ deg_in,
    const float* __restrict__ norm_src, const float* __restrict__ norm_dst,
    float* __restrict__ agg) {
  int wave = (blockIdx.x * blockDim.x + threadIdx.x) >> 6;
  int lane = threadIdx.x & 63;
  if (wave >= N_NODES) return;
  int v = wave;
  float2 a = ((const float2*)(x + (size_t)v * IN_DIM))[lane];
  float ns = norm_src[v];
  float2 acc;
  acc.x = a.x * ns;
  acc.y = a.y * ns;
  int beg = offs[v];
  int end = beg + deg_in[v];
  for (int e = beg; e < end; e++) {
    int u = edge_src[e];                       // wave-uniform
    float nsu = norm_src[u];
    float2 xu = ((const float2*)(x + (size_t)u * IN_DIM))[lane];
    acc.x += xu.x * nsu;
    acc.y += xu.y * nsu;
  }
  float nd = norm_dst[v];
  acc.x *= nd;
  acc.y *= nd;
  ((float2*)(agg + (size_t)v * IN_DIM))[lane] = acc;
}

// ------ K7: f32 GEMM (64x64 tile, K=128 in LDS) + bias + ReLU + fused ------
// per-graph max-pool via uint atomicMax (valid: post-ReLU values >= 0)
#define BM 64
#define BN 64
__global__ __launch_bounds__(256) void k_gemm_pool(
    const float* __restrict__ agg, const float* __restrict__ W,
    const float* __restrict__ bias, const int* __restrict__ graph_ids,
    float* __restrict__ hg) {
  __shared__ float A[BM][IN_DIM + 4];  // +4 pad: conflict-free & 16B-aligned rows
  __shared__ float B[IN_DIM][BN];

  int r0 = blockIdx.x * BM;
  int c0 = blockIdx.y * BN;
  int t = threadIdx.x;

  // stage A: 64 rows x 128 k, float4 per thread x 8
  {
    int tr = t >> 5;          // 0..7
    int tk = (t & 31) << 2;   // 0,4,..,124
#pragma unroll
    for (int it = 0; it < 8; it++) {
      int rl = tr + it * 8;
      int row = r0 + rl;
      int srow = row < N_NODES ? row : N_NODES - 1;  // clamp; epilogue guards
      float4 vv = *(const float4*)&agg[(size_t)srow * IN_DIM + tk];
      *(float4*)&A[rl][tk] = vv;
    }
  }
  // stage B: 128 k x 64 cols
  {
    int bk = t >> 4;          // 0..15
    int bcc = (t & 15) << 2;  // 0,4,..,60
#pragma unroll
    for (int it = 0; it < 8; it++) {
      int k = bk + it * 16;
      float4 vv = *(const float4*)&W[(size_t)k * HID + c0 + bcc];
      *(float4*)&B[k][bcc] = vv;
    }
  }
  __syncthreads();

  int tx = t & 15;  // col group
  int ty = t >> 4;  // row group
  float acc[4][4] = {{0.f}};

#pragma unroll
  for (int k0 = 0; k0 < IN_DIM; k0 += 4) {
    float4 b0 = *(float4*)&B[k0 + 0][tx * 4];
    float4 b1 = *(float4*)&B[k0 + 1][tx * 4];
    float4 b2 = *(float4*)&B[k0 + 2][tx * 4];
    float4 b3 = *(float4*)&B[k0 + 3][tx * 4];
#pragma unroll
    for (int i = 0; i < 4; i++) {
      float4 av = *(float4*)&A[ty * 4 + i][k0];
      acc[i][0] += av.x * b0.x + av.y * b1.x + av.z * b2.x + av.w * b3.x;
      acc[i][1] += av.x * b0.y + av.y * b1.y + av.z * b2.y + av.w * b3.y;
      acc[i][2] += av.x * b0.z + av.y * b1.z + av.z * b2.z + av.w * b3.z;
      acc[i][3] += av.x * b0.w + av.y * b1.w + av.z * b2.w + av.w * b3.w;
    }
  }

  // epilogue: bias + relu + per-graph max (merge consecutive same-graph rows)
  int gid[4];
#pragma unroll
  for (int i = 0; i < 4; i++) {
    int row = r0 + ty * 4 + i;
    gid[i] = (row < N_NODES) ? graph_ids[row] : -1;
  }
#pragma unroll
  for (int j = 0; j < 4; j++) {
    int c = c0 + tx * 4 + j;
    float bia = bias[c];
    float v[4];
#pragma unroll
    for (int i = 0; i < 4; i++) v[i] = fmaxf(acc[i][j] + bia, 0.0f);
    int i = 0;
    while (i < 4) {
      int g = gid[i];
      if (g < 0) { i++; continue; }
      float m = v[i];
      int i2 = i + 1;
      while (i2 < 4 && gid[i2] == g) { m = fmaxf(m, v[i2]); i2++; }
      atomicMax((unsigned int*)&hg[g * HID + c], __float_as_uint(m));
      i = i2;
    }
  }
}

// ---------- K8: tiny classifier GEMM + log_softmax. 1 block, 64 thr ----------
__global__ void k_classify(const float* __restrict__ hg, const float* __restrict__ Wc,
                           const float* __restrict__ bc, float* __restrict__ out) {
  int g = threadIdx.x;
  if (g >= N_GRAPHS) return;
  float logits[NCLS];
#pragma unroll
  for (int c = 0; c < NCLS; c++) logits[c] = bc[c];
  for (int k = 0; k < HID; k++) {
    float h = hg[g * HID + k];
#pragma unroll
    for (int c = 0; c < NCLS; c++) logits[c] += h * Wc[k * NCLS + c];
  }
  float m = logits[0];
#pragma unroll
  for (int c = 1; c < NCLS; c++) m = fmaxf(m, logits[c]);
  float s = 0.f;
#pragma unroll
  for (int c = 0; c < NCLS; c++) s += expf(logits[c] - m);
  float lse = logf(s) + m;
#pragma unroll
  for (int c = 0; c < NCLS; c++) out[g * NCLS + c] = logits[c] - lse;
}

extern "C" void kernel_launch(void* const* d_in, const int* in_sizes, int n_in,
                              void* d_out, int out_size, void* d_ws, size_t ws_size,
                              hipStream_t stream) {
  const float* x = (const float*)d_in[0];
  const int* src = (const int*)d_in[1];
  const int* dst = (const int*)d_in[2];
  const int* graph_ids = (const int*)d_in[3];
  const float* W = (const float*)d_in[4];
  const float* b = (const float*)d_in[5];
  const float* Wc = (const float*)d_in[6];
  const float* bc = (const float*)d_in[7];
  float* out = (float*)d_out;

  // ---- workspace layout (~60 MB total) ----
  int* deg_out = (int*)d_ws;                  // 100000
  int* deg_in = deg_out + N_NODES;            // 100000
  float* hg = (float*)(deg_in + N_NODES);     // 64*256 = 16384
  float* norm_src = hg + N_GRAPHS * HID;      // 100000
  float* norm_dst = norm_src + N_NODES;       // 100000
  int* offs = (int*)(norm_dst + N_NODES);     // 100000
  int* cursor = offs + N_NODES;               // 100000
  int* blockSums = cursor + N_NODES;          // 128
  int* edge_src = blockSums + 128;            // 1600000
  float* agg = (float*)(edge_src + N_EDGES);  // 100000*128

  // zero deg_out, deg_in, hg (contiguous prefix of ws)
  size_t zbytes = (size_t)(2 * N_NODES + N_GRAPHS * HID) * 4;
  hipMemsetAsync(d_ws, 0, zbytes, stream);

  k_degrees<<<2048, 256, 0, stream>>>(src, dst, deg_out, deg_in);
  k_scan1<<<SCAN_BLOCKS, 256, 0, stream>>>(deg_in, offs, blockSums);
  k_scan2<<<1, 128, 0, stream>>>(blockSums);
  k_finalize<<<(N_NODES + 255) / 256, 256, 0, stream>>>(deg_out, deg_in, blockSums,
                                                        offs, cursor, norm_src, norm_dst);
  k_scatter<<<2048, 256, 0, stream>>>(src, dst, cursor, edge_src);
  k_aggregate<<<N_NODES / 4, 256, 0, stream>>>(x, edge_src, offs, deg_in,
                                               norm_src, norm_dst, agg);
  dim3 ggrid((N_NODES + BM - 1) / BM, HID / BN);
  k_gemm_pool<<<ggrid, 256, 0, stream>>>(agg, W, b, graph_ids, hg);
  k_classify<<<1, 64, 0, stream>>>(hg, Wc, bc, out);
}

// Round 2
// 858.471 us; speedup vs baseline: 5.0402x; 5.0402x over previous
//
#include <hip/hip_runtime.h>
#include <hip/hip_bf16.h>
#include <math.h>

#define N_NODES 100000
#define N_EDGES 1600000
#define N_GRAPHS 64
#define IN_DIM 128
#define HID 256
#define NCLS 16

#define SCAN_CHUNK 1024
#define SCAN_BLOCKS ((N_NODES + SCAN_CHUNK - 1) / SCAN_CHUNK)  // 98

// ---------------- K1: degree count (int atomics, cheap) ----------------
__global__ void k_degrees(const int* __restrict__ src, const int* __restrict__ dst,
                          int* __restrict__ deg_out, int* __restrict__ deg_in) {
  int i = blockIdx.x * blockDim.x + threadIdx.x;
  int stride = gridDim.x * blockDim.x;
  for (; i < N_EDGES; i += stride) {
    atomicAdd(&deg_out[src[i]], 1);
    atomicAdd(&deg_in[dst[i]], 1);
  }
}

// ---------------- K2: per-chunk exclusive scan of deg_in ----------------
__global__ void k_scan1(const int* __restrict__ deg_in, int* __restrict__ offs,
                        int* __restrict__ blockSums) {
  __shared__ int sdata[256];
  int b = blockIdx.x, t = threadIdx.x;
  int base = b * SCAN_CHUNK + t * 4;
  int v[4];
#pragma unroll
  for (int j = 0; j < 4; j++) {
    int idx = base + j;
    v[j] = (idx < N_NODES) ? deg_in[idx] : 0;
  }
  int tsum = v[0] + v[1] + v[2] + v[3];
  sdata[t] = tsum;
  __syncthreads();
  for (int off = 1; off < 256; off <<= 1) {
    int x = sdata[t];
    int y = (t >= off) ? sdata[t - off] : 0;
    __syncthreads();
    sdata[t] = x + y;
    __syncthreads();
  }
  int run = sdata[t] - tsum;  // exclusive prefix of this thread's chunk
#pragma unroll
  for (int j = 0; j < 4; j++) {
    int idx = base + j;
    if (idx < N_NODES) offs[idx] = run;
    run += v[j];
  }
  if (t == 255) blockSums[b] = sdata[255];
}

// ---------------- K3: scan the 98 block sums (one block) ----------------
__global__ void k_scan2(int* __restrict__ blockSums) {
  __shared__ int sdata[128];
  int t = threadIdx.x;
  int v = (t < SCAN_BLOCKS) ? blockSums[t] : 0;
  sdata[t] = v;
  __syncthreads();
  for (int off = 1; off < 128; off <<= 1) {
    int x = sdata[t];
    int y = (t >= off) ? sdata[t - off] : 0;
    __syncthreads();
    sdata[t] = x + y;
    __syncthreads();
  }
  if (t < SCAN_BLOCKS) blockSums[t] = sdata[t] - v;  // exclusive
}

// ------- K4: finalize offsets, init cursors, compute D^-1/2 norms -------
__global__ void k_finalize(const int* __restrict__ deg_out, const int* __restrict__ deg_in,
                           const int* __restrict__ blockSums,
                           int* __restrict__ offs, int* __restrict__ cursor,
                           float* __restrict__ norm_src, float* __restrict__ norm_dst) {
  int i = blockIdx.x * blockDim.x + threadIdx.x;
  if (i >= N_NODES) return;
  int o = offs[i] + blockSums[i / SCAN_CHUNK];
  offs[i] = o;
  cursor[i] = o;
  norm_src[i] = rsqrtf((float)deg_out[i] + 1.0f);  // self-loop adds +1
  norm_dst[i] = rsqrtf((float)deg_in[i] + 1.0f);
}

// ---------------- K5: scatter edges into CSR buckets by dst ----------------
__global__ void k_scatter(const int* __restrict__ src, const int* __restrict__ dst,
                          int* __restrict__ cursor, int* __restrict__ edge_src) {
  int i = blockIdx.x * blockDim.x + threadIdx.x;
  int stride = gridDim.x * blockDim.x;
  for (; i < N_EDGES; i += stride) {
    int d = dst[i];
    int pos = atomicAdd(&cursor[d], 1);
    edge_src[pos] = src[i];
  }
}

// --------- K6: pull-aggregate. One wave per node, float2 per lane ---------
// agg[v] = norm_dst[v] * ( x[v]*norm_src[v] + sum_{u->v} x[u]*norm_src[u] )
__global__ __launch_bounds__(256) void k_aggregate(
    const float* __restrict__ x, const int* __restrict__ edge_src,
    const int* __restrict__ offs, const int* __restrict__ deg_in,
    const float* __restrict__ norm_src, const float* __restrict__ norm_dst,
    float* __restrict__ agg) {
  int wave = (blockIdx.x * blockDim.x + threadIdx.x) >> 6;
  int lane = threadIdx.x & 63;
  if (wave >= N_NODES) return;
  int v = wave;
  float2 a = ((const float2*)(x + (size_t)v * IN_DIM))[lane];
  float ns = norm_src[v];
  float2 acc;
  acc.x = a.x * ns;
  acc.y = a.y * ns;
  int beg = offs[v];
  int end = beg + deg_in[v];
  for (int e = beg; e < end; e++) {
    int u = edge_src[e];                       // wave-uniform
    float nsu = norm_src[u];
    float2 xu = ((const float2*)(x + (size_t)u * IN_DIM))[lane];
    acc.x += xu.x * nsu;
    acc.y += xu.y * nsu;
  }
  float nd = norm_dst[v];
  acc.x *= nd;
  acc.y *= nd;
  ((float2*)(agg + (size_t)v * IN_DIM))[lane] = acc;
}

// ------ K7: f32 GEMM (64x64 tile, K=128 in LDS) + bias + ReLU + fused ------
// per-graph max-pool via uint atomicMax (valid: post-ReLU values >= 0)
// NOTE: unroll capped at 2. Full unroll (R1) hoisted 128 LDS loads, hit the
// 256-VGPR cap and spilled ~10 GB/dispatch to scratch (3833 us, VALUBusy 5%).
#define BM 64
#define BN 64
__global__ __launch_bounds__(256, 2) void k_gemm_pool(
    const float* __restrict__ agg, const float* __restrict__ W,
    const float* __restrict__ bias, const int* __restrict__ graph_ids,
    float* __restrict__ hg) {
  __shared__ float A[BM][IN_DIM + 4];  // +4 pad: conflict-free & 16B-aligned rows
  __shared__ float B[IN_DIM][BN];

  int r0 = blockIdx.x * BM;
  int c0 = blockIdx.y * BN;
  int t = threadIdx.x;

  // stage A: 64 rows x 128 k, float4 per thread x 8
  {
    int tr = t >> 5;          // 0..7
    int tk = (t & 31) << 2;   // 0,4,..,124
#pragma unroll
    for (int it = 0; it < 8; it++) {
      int rl = tr + it * 8;
      int row = r0 + rl;
      int srow = row < N_NODES ? row : N_NODES - 1;  // clamp; epilogue guards
      float4 vv = *(const float4*)&agg[(size_t)srow * IN_DIM + tk];
      *(float4*)&A[rl][tk] = vv;
    }
  }
  // stage B: 128 k x 64 cols
  {
    int bk = t >> 4;          // 0..15
    int bcc = (t & 15) << 2;  // 0,4,..,60
#pragma unroll
    for (int it = 0; it < 8; it++) {
      int k = bk + it * 16;
      float4 vv = *(const float4*)&W[(size_t)k * HID + c0 + bcc];
      *(float4*)&B[k][bcc] = vv;
    }
  }
  __syncthreads();

  int tx = t & 15;  // col group
  int ty = t >> 4;  // row group
  float acc[4][4] = {{0.f}};

#pragma unroll 2
  for (int k0 = 0; k0 < IN_DIM; k0 += 4) {
    float4 b0 = *(float4*)&B[k0 + 0][tx * 4];
    float4 b1 = *(float4*)&B[k0 + 1][tx * 4];
    float4 b2 = *(float4*)&B[k0 + 2][tx * 4];
    float4 b3 = *(float4*)&B[k0 + 3][tx * 4];
#pragma unroll
    for (int i = 0; i < 4; i++) {
      float4 av = *(float4*)&A[ty * 4 + i][k0];
      acc[i][0] += av.x * b0.x + av.y * b1.x + av.z * b2.x + av.w * b3.x;
      acc[i][1] += av.x * b0.y + av.y * b1.y + av.z * b2.y + av.w * b3.y;
      acc[i][2] += av.x * b0.z + av.y * b1.z + av.z * b2.z + av.w * b3.z;
      acc[i][3] += av.x * b0.w + av.y * b1.w + av.z * b2.w + av.w * b3.w;
    }
  }

  // epilogue: bias + relu + per-graph max (merge consecutive same-graph rows)
  int gid[4];
#pragma unroll
  for (int i = 0; i < 4; i++) {
    int row = r0 + ty * 4 + i;
    gid[i] = (row < N_NODES) ? graph_ids[row] : -1;
  }
#pragma unroll
  for (int j = 0; j < 4; j++) {
    int c = c0 + tx * 4 + j;
    float bia = bias[c];
    float v[4];
#pragma unroll
    for (int i = 0; i < 4; i++) v[i] = fmaxf(acc[i][j] + bia, 0.0f);
    int i = 0;
    while (i < 4) {
      int g = gid[i];
      if (g < 0) { i++; continue; }
      float m = v[i];
      int i2 = i + 1;
      while (i2 < 4 && gid[i2] == g) { m = fmaxf(m, v[i2]); i2++; }
      atomicMax((unsigned int*)&hg[g * HID + c], __float_as_uint(m));
      i = i2;
    }
  }
}

// ---------- K8: tiny classifier GEMM + log_softmax. 1 block, 64 thr ----------
__global__ void k_classify(const float* __restrict__ hg, const float* __restrict__ Wc,
                           const float* __restrict__ bc, float* __restrict__ out) {
  int g = threadIdx.x;
  if (g >= N_GRAPHS) return;
  float logits[NCLS];
#pragma unroll
  for (int c = 0; c < NCLS; c++) logits[c] = bc[c];
  for (int k = 0; k < HID; k++) {
    float h = hg[g * HID + k];
#pragma unroll
    for (int c = 0; c < NCLS; c++) logits[c] += h * Wc[k * NCLS + c];
  }
  float m = logits[0];
#pragma unroll
  for (int c = 1; c < NCLS; c++) m = fmaxf(m, logits[c]);
  float s = 0.f;
#pragma unroll
  for (int c = 0; c < NCLS; c++) s += expf(logits[c] - m);
  float lse = logf(s) + m;
#pragma unroll
  for (int c = 0; c < NCLS; c++) out[g * NCLS + c] = logits[c] - lse;
}

extern "C" void kernel_launch(void* const* d_in, const int* in_sizes, int n_in,
                              void* d_out, int out_size, void* d_ws, size_t ws_size,
                              hipStream_t stream) {
  const float* x = (const float*)d_in[0];
  const int* src = (const int*)d_in[1];
  const int* dst = (const int*)d_in[2];
  const int* graph_ids = (const int*)d_in[3];
  const float* W = (const float*)d_in[4];
  const float* b = (const float*)d_in[5];
  const float* Wc = (const float*)d_in[6];
  const float* bc = (const float*)d_in[7];
  float* out = (float*)d_out;

  // ---- workspace layout (~60 MB total) ----
  int* deg_out = (int*)d_ws;                  // 100000
  int* deg_in = deg_out + N_NODES;            // 100000
  float* hg = (float*)(deg_in + N_NODES);     // 64*256 = 16384
  float* norm_src = hg + N_GRAPHS * HID;      // 100000
  float* norm_dst = norm_src + N_NODES;       // 100000
  int* offs = (int*)(norm_dst + N_NODES);     // 100000
  int* cursor = offs + N_NODES;               // 100000
  int* blockSums = cursor + N_NODES;          // 128
  int* edge_src = blockSums + 128;            // 1600000
  float* agg = (float*)(edge_src + N_EDGES);  // 100000*128

  // zero deg_out, deg_in, hg (contiguous prefix of ws)
  size_t zbytes = (size_t)(2 * N_NODES + N_GRAPHS * HID) * 4;
  hipMemsetAsync(d_ws, 0, zbytes, stream);

  k_degrees<<<2048, 256, 0, stream>>>(src, dst, deg_out, deg_in);
  k_scan1<<<SCAN_BLOCKS, 256, 0, stream>>>(deg_in, offs, blockSums);
  k_scan2<<<1, 128, 0, stream>>>(blockSums);
  k_finalize<<<(N_NODES + 255) / 256, 256, 0, stream>>>(deg_out, deg_in, blockSums,
                                                        offs, cursor, norm_src, norm_dst);
  k_scatter<<<2048, 256, 0, stream>>>(src, dst, cursor, edge_src);
  k_aggregate<<<N_NODES / 4, 256, 0, stream>>>(x, edge_src, offs, deg_in,
                                               norm_src, norm_dst, agg);
  dim3 ggrid((N_NODES + BM - 1) / BM, HID / BN);
  k_gemm_pool<<<ggrid, 256, 0, stream>>>(agg, W, b, graph_ids, hg);
  k_classify<<<1, 64, 0, stream>>>(hg, Wc, bc, out);
}

// Round 3
// 591.782 us; speedup vs baseline: 7.3116x; 1.4507x over previous
//
#include <hip/hip_runtime.h>
#include <hip/hip_bf16.h>
#include <math.h>

#define N_NODES 100000
#define N_EDGES 1600000
#define N_GRAPHS 64
#define IN_DIM 128
#define HID 256
#define NCLS 16

#define SCAN_CHUNK 1024
#define SCAN_BLOCKS ((N_NODES + SCAN_CHUNK - 1) / SCAN_CHUNK)  // 98

// ---------------- K1: degree count (int atomics, cheap) ----------------
__global__ void k_degrees(const int* __restrict__ src, const int* __restrict__ dst,
                          int* __restrict__ deg_out, int* __restrict__ deg_in) {
  int i = blockIdx.x * blockDim.x + threadIdx.x;
  int stride = gridDim.x * blockDim.x;
  for (; i < N_EDGES; i += stride) {
    atomicAdd(&deg_out[src[i]], 1);
    atomicAdd(&deg_in[dst[i]], 1);
  }
}

// ---------------- K2: per-chunk exclusive scan of deg_in ----------------
__global__ void k_scan1(const int* __restrict__ deg_in, int* __restrict__ offs,
                        int* __restrict__ blockSums) {
  __shared__ int sdata[256];
  int b = blockIdx.x, t = threadIdx.x;
  int base = b * SCAN_CHUNK + t * 4;
  int v[4];
#pragma unroll
  for (int j = 0; j < 4; j++) {
    int idx = base + j;
    v[j] = (idx < N_NODES) ? deg_in[idx] : 0;
  }
  int tsum = v[0] + v[1] + v[2] + v[3];
  sdata[t] = tsum;
  __syncthreads();
  for (int off = 1; off < 256; off <<= 1) {
    int x = sdata[t];
    int y = (t >= off) ? sdata[t - off] : 0;
    __syncthreads();
    sdata[t] = x + y;
    __syncthreads();
  }
  int run = sdata[t] - tsum;  // exclusive prefix of this thread's chunk
#pragma unroll
  for (int j = 0; j < 4; j++) {
    int idx = base + j;
    if (idx < N_NODES) offs[idx] = run;
    run += v[j];
  }
  if (t == 255) blockSums[b] = sdata[255];
}

// ---------------- K3: scan the 98 block sums (one block) ----------------
__global__ void k_scan2(int* __restrict__ blockSums) {
  __shared__ int sdata[128];
  int t = threadIdx.x;
  int v = (t < SCAN_BLOCKS) ? blockSums[t] : 0;
  sdata[t] = v;
  __syncthreads();
  for (int off = 1; off < 128; off <<= 1) {
    int x = sdata[t];
    int y = (t >= off) ? sdata[t - off] : 0;
    __syncthreads();
    sdata[t] = x + y;
    __syncthreads();
  }
  if (t < SCAN_BLOCKS) blockSums[t] = sdata[t] - v;  // exclusive
}

// ------- K4: finalize offsets, init cursors, compute D^-1/2 norms -------
__global__ void k_finalize(const int* __restrict__ deg_out, const int* __restrict__ deg_in,
                           const int* __restrict__ blockSums,
                           int* __restrict__ offs, int* __restrict__ cursor,
                           float* __restrict__ norm_src, float* __restrict__ norm_dst) {
  int i = blockIdx.x * blockDim.x + threadIdx.x;
  if (i >= N_NODES) return;
  int o = offs[i] + blockSums[i / SCAN_CHUNK];
  offs[i] = o;
  cursor[i] = o;
  norm_src[i] = rsqrtf((float)deg_out[i] + 1.0f);  // self-loop adds +1
  norm_dst[i] = rsqrtf((float)deg_in[i] + 1.0f);
}

// ---------------- K5: scatter edges into CSR buckets by dst ----------------
__global__ void k_scatter(const int* __restrict__ src, const int* __restrict__ dst,
                          int* __restrict__ cursor, int* __restrict__ edge_src) {
  int i = blockIdx.x * blockDim.x + threadIdx.x;
  int stride = gridDim.x * blockDim.x;
  for (; i < N_EDGES; i += stride) {
    int d = dst[i];
    int pos = atomicAdd(&cursor[d], 1);
    edge_src[pos] = src[i];
  }
}

// --------- K6: pull-aggregate. One wave per node, float2 per lane ---------
// agg[v] = norm_dst[v] * ( x[v]*norm_src[v] + sum_{u->v} x[u]*norm_src[u] )
// Unroll 4: the per-edge chain (u -> norm_src[u] -> x[u]) allows only one
// outstanding gather per wave; 4 independent chains hide L2/L3 latency.
__global__ __launch_bounds__(256) void k_aggregate(
    const float* __restrict__ x, const int* __restrict__ edge_src,
    const int* __restrict__ offs, const int* __restrict__ deg_in,
    const float* __restrict__ norm_src, const float* __restrict__ norm_dst,
    float* __restrict__ agg) {
  int wave = (blockIdx.x * blockDim.x + threadIdx.x) >> 6;
  int lane = threadIdx.x & 63;
  if (wave >= N_NODES) return;
  int v = wave;
  float2 a = ((const float2*)(x + (size_t)v * IN_DIM))[lane];
  float ns = norm_src[v];
  float accx = a.x * ns, accy = a.y * ns;
  int beg = offs[v];
  int deg = deg_in[v];
  int e = beg;
  int end4 = beg + (deg & ~3);
  for (; e < end4; e += 4) {
    int u0 = edge_src[e + 0];
    int u1 = edge_src[e + 1];
    int u2 = edge_src[e + 2];
    int u3 = edge_src[e + 3];
    float n0 = norm_src[u0], n1 = norm_src[u1], n2 = norm_src[u2], n3 = norm_src[u3];
    float2 x0 = ((const float2*)(x + (size_t)u0 * IN_DIM))[lane];
    float2 x1 = ((const float2*)(x + (size_t)u1 * IN_DIM))[lane];
    float2 x2 = ((const float2*)(x + (size_t)u2 * IN_DIM))[lane];
    float2 x3 = ((const float2*)(x + (size_t)u3 * IN_DIM))[lane];
    accx += x0.x * n0 + x1.x * n1 + x2.x * n2 + x3.x * n3;
    accy += x0.y * n0 + x1.y * n1 + x2.y * n2 + x3.y * n3;
  }
  int end = beg + deg;
  for (; e < end; e++) {
    int u = edge_src[e];
    float nu = norm_src[u];
    float2 xu = ((const float2*)(x + (size_t)u * IN_DIM))[lane];
    accx += xu.x * nu;
    accy += xu.y * nu;
  }
  float nd = norm_dst[v];
  float2 outv;
  outv.x = accx * nd;
  outv.y = accy * nd;
  ((float2*)(agg + (size_t)v * IN_DIM))[lane] = outv;
}

// ------ K7: f32 GEMM 128x128 tile, 8x8 micro, BK=32 + bias + ReLU + pool ------
// R2 post-mortem: 4x4 micro = 2 B LDS per FMA -> LDS-BW-bound, VALUBusy 25%.
// 8x8 micro (split 4+4 at stride 64, keeping the conflict-free tx*4 b128
// pattern) = 1 B/FMA -> LDS ~ VALU balance. A staged k-major (transpose) so
// A-frags are b128 too. Pool: shfl+LDS block reduction, then 1 atomic/col/graph
// (R2: 6.4M atomics = 100 MB HBM writes; now ~0.2M).
#define BM 128
#define BN 128
#define BK 32
#define LDT 132  // padded leading dim for As/Bs (132%4==0 keeps b128 alignment)

__global__ __launch_bounds__(256, 4) void k_gemm_pool(
    const float* __restrict__ agg, const float* __restrict__ W,
    const float* __restrict__ bias, const int* __restrict__ graph_ids,
    float* __restrict__ hg) {
  __shared__ float As[BK][LDT];  // k-major: As[k][row], 16.9 KB
  __shared__ float Bs[BK][LDT];  // Bs[k][col], 16.9 KB
  __shared__ float red[4][BN];   // pooling cross-wave reduce, 2 KB

  int r0 = blockIdx.x * BM;
  int c0 = blockIdx.y * BN;
  int t = threadIdx.x;
  int tx = t & 15;   // col group
  int ty = t >> 4;   // row group

  float acc[8][8];
#pragma unroll
  for (int i = 0; i < 8; i++)
#pragma unroll
    for (int j = 0; j < 8; j++) acc[i][j] = 0.f;

  for (int kp = 0; kp < IN_DIM; kp += BK) {
    // stage A with transpose: 128 rows x 32 k -> As[k][row]
    {
      int kq = (t & 7) << 2;  // 0,4,..,28
      int row = t >> 3;       // 0..31
#pragma unroll
      for (int it = 0; it < 4; it++) {
        int rl = row + it * 32;
        int grow = r0 + rl;
        int srow = grow < N_NODES ? grow : N_NODES - 1;  // clamp; pool guards
        float4 vv = *(const float4*)&agg[(size_t)srow * IN_DIM + kp + kq];
        As[kq + 0][rl] = vv.x;
        As[kq + 1][rl] = vv.y;
        As[kq + 2][rl] = vv.z;
        As[kq + 3][rl] = vv.w;
      }
    }
    // stage B: 32 k x 128 cols (row-major, direct)
    {
      int cc = (t & 31) << 2;  // 0..124
      int kk = t >> 5;         // 0..7
#pragma unroll
      for (int it = 0; it < 4; it++) {
        int kl = kk + it * 8;
        float4 vv = *(const float4*)&W[(size_t)(kp + kl) * HID + c0 + cc];
        *(float4*)&Bs[kl][cc] = vv;
      }
    }
    __syncthreads();

#pragma unroll 2
    for (int kk = 0; kk < BK; kk++) {
      float4 a0 = *(float4*)&As[kk][ty * 4];
      float4 a1 = *(float4*)&As[kk][64 + ty * 4];
      float4 b0 = *(float4*)&Bs[kk][tx * 4];
      float4 b1 = *(float4*)&Bs[kk][64 + tx * 4];
      float av[8] = {a0.x, a0.y, a0.z, a0.w, a1.x, a1.y, a1.z, a1.w};
      float bv[8] = {b0.x, b0.y, b0.z, b0.w, b1.x, b1.y, b1.z, b1.w};
#pragma unroll
      for (int i = 0; i < 8; i++)
#pragma unroll
        for (int j = 0; j < 8; j++) acc[i][j] += av[i] * bv[j];
    }
    __syncthreads();
  }

  // ---- epilogue: bias + relu in place ----
  float bias_v[8];
#pragma unroll
  for (int j = 0; j < 8; j++) {
    int c = c0 + ((j < 4) ? (tx * 4 + j) : (64 + tx * 4 + j - 4));
    bias_v[j] = bias[c];
  }
  int gid[8];
#pragma unroll
  for (int i = 0; i < 8; i++) {
    int r = r0 + ((i < 4) ? (ty * 4 + i) : (64 + ty * 4 + i - 4));
    gid[i] = (r < N_NODES) ? graph_ids[r] : -1;
  }
#pragma unroll
  for (int i = 0; i < 8; i++)
#pragma unroll
    for (int j = 0; j < 8; j++) acc[i][j] = fmaxf(acc[i][j] + bias_v[j], 0.f);

  // ---- fused max-pool: per-graph block reduction, then 1 atomic/col ----
  // graph_ids sorted -> block spans [gmin, gmax], nearly always <= 2 graphs
  int gmin = graph_ids[r0];
  int rlast = r0 + BM - 1;
  if (rlast >= N_NODES) rlast = N_NODES - 1;
  int gmax = graph_ids[rlast];
  int w = t >> 6;  // wave id 0..3

  for (int g = gmin; g <= gmax; g++) {
    float m[8];
#pragma unroll
    for (int j = 0; j < 8; j++) m[j] = 0.f;  // relu output >= 0, so 0 is identity
#pragma unroll
    for (int i = 0; i < 8; i++) {
      if (gid[i] == g) {
#pragma unroll
        for (int j = 0; j < 8; j++) m[j] = fmaxf(m[j], acc[i][j]);
      }
    }
    // reduce across the 4 ty values within the wave (lanes ^16, ^32)
#pragma unroll
    for (int j = 0; j < 8; j++) {
      m[j] = fmaxf(m[j], __shfl_xor(m[j], 16, 64));
      m[j] = fmaxf(m[j], __shfl_xor(m[j], 32, 64));
    }
    if ((t & 63) < 16) {
#pragma unroll
      for (int j = 0; j < 8; j++) {
        int cl = (j < 4) ? (tx * 4 + j) : (64 + tx * 4 + j - 4);
        red[w][cl] = m[j];
      }
    }
    __syncthreads();
    if (t < BN) {
      float mm = fmaxf(fmaxf(red[0][t], red[1][t]), fmaxf(red[2][t], red[3][t]));
      atomicMax((unsigned int*)&hg[g * HID + c0 + t], __float_as_uint(mm));
    }
    __syncthreads();
  }
}

// ---------- K8: tiny classifier GEMM + log_softmax. 1 block, 64 thr ----------
__global__ void k_classify(const float* __restrict__ hg, const float* __restrict__ Wc,
                           const float* __restrict__ bc, float* __restrict__ out) {
  int g = threadIdx.x;
  if (g >= N_GRAPHS) return;
  float logits[NCLS];
#pragma unroll
  for (int c = 0; c < NCLS; c++) logits[c] = bc[c];
  for (int k = 0; k < HID; k++) {
    float h = hg[g * HID + k];
#pragma unroll
    for (int c = 0; c < NCLS; c++) logits[c] += h * Wc[k * NCLS + c];
  }
  float m = logits[0];
#pragma unroll
  for (int c = 1; c < NCLS; c++) m = fmaxf(m, logits[c]);
  float s = 0.f;
#pragma unroll
  for (int c = 0; c < NCLS; c++) s += expf(logits[c] - m);
  float lse = logf(s) + m;
#pragma unroll
  for (int c = 0; c < NCLS; c++) out[g * NCLS + c] = logits[c] - lse;
}

extern "C" void kernel_launch(void* const* d_in, const int* in_sizes, int n_in,
                              void* d_out, int out_size, void* d_ws, size_t ws_size,
                              hipStream_t stream) {
  const float* x = (const float*)d_in[0];
  const int* src = (const int*)d_in[1];
  const int* dst = (const int*)d_in[2];
  const int* graph_ids = (const int*)d_in[3];
  const float* W = (const float*)d_in[4];
  const float* b = (const float*)d_in[5];
  const float* Wc = (const float*)d_in[6];
  const float* bc = (const float*)d_in[7];
  float* out = (float*)d_out;

  // ---- workspace layout (~60 MB total) ----
  int* deg_out = (int*)d_ws;                  // 100000
  int* deg_in = deg_out + N_NODES;            // 100000
  float* hg = (float*)(deg_in + N_NODES);     // 64*256 = 16384
  float* norm_src = hg + N_GRAPHS * HID;      // 100000
  float* norm_dst = norm_src + N_NODES;       // 100000
  int* offs = (int*)(norm_dst + N_NODES);     // 100000
  int* cursor = offs + N_NODES;               // 100000
  int* blockSums = cursor + N_NODES;          // 128
  int* edge_src = blockSums + 128;            // 1600000
  float* agg = (float*)(edge_src + N_EDGES);  // 100000*128

  // zero deg_out, deg_in, hg (contiguous prefix of ws)
  size_t zbytes = (size_t)(2 * N_NODES + N_GRAPHS * HID) * 4;
  hipMemsetAsync(d_ws, 0, zbytes, stream);

  k_degrees<<<2048, 256, 0, stream>>>(src, dst, deg_out, deg_in);
  k_scan1<<<SCAN_BLOCKS, 256, 0, stream>>>(deg_in, offs, blockSums);
  k_scan2<<<1, 128, 0, stream>>>(blockSums);
  k_finalize<<<(N_NODES + 255) / 256, 256, 0, stream>>>(deg_out, deg_in, blockSums,
                                                        offs, cursor, norm_src, norm_dst);
  k_scatter<<<2048, 256, 0, stream>>>(src, dst, cursor, edge_src);
  k_aggregate<<<N_NODES / 4, 256, 0, stream>>>(x, edge_src, offs, deg_in,
                                               norm_src, norm_dst, agg);
  dim3 ggrid((N_NODES + BM - 1) / BM, HID / BN);
  k_gemm_pool<<<ggrid, 256, 0, stream>>>(agg, W, b, graph_ids, hg);
  k_classify<<<1, 64, 0, stream>>>(hg, Wc, bc, out);
}

// Round 4
// 530.429 us; speedup vs baseline: 8.1573x; 1.1157x over previous
//
#include <hip/hip_runtime.h>
#include <hip/hip_bf16.h>
#include <math.h>

#define N_NODES 100000
#define N_EDGES 1600000
#define N_GRAPHS 64
#define IN_DIM 128
#define HID 256
#define NCLS 16

#define SCAN_CHUNK 1024
#define SCAN_BLOCKS ((N_NODES + SCAN_CHUNK - 1) / SCAN_CHUNK)  // 98

// ---------------- K1: degree count (int atomics, cheap) ----------------
__global__ void k_degrees(const int* __restrict__ src, const int* __restrict__ dst,
                          int* __restrict__ deg_out, int* __restrict__ deg_in) {
  int i = blockIdx.x * blockDim.x + threadIdx.x;
  int stride = gridDim.x * blockDim.x;
  for (; i < N_EDGES; i += stride) {
    atomicAdd(&deg_out[src[i]], 1);
    atomicAdd(&deg_in[dst[i]], 1);
  }
}

// ---------------- K2: per-chunk exclusive scan of deg_in ----------------
__global__ void k_scan1(const int* __restrict__ deg_in, int* __restrict__ offs,
                        int* __restrict__ blockSums) {
  __shared__ int sdata[256];
  int b = blockIdx.x, t = threadIdx.x;
  int base = b * SCAN_CHUNK + t * 4;
  int v[4];
#pragma unroll
  for (int j = 0; j < 4; j++) {
    int idx = base + j;
    v[j] = (idx < N_NODES) ? deg_in[idx] : 0;
  }
  int tsum = v[0] + v[1] + v[2] + v[3];
  sdata[t] = tsum;
  __syncthreads();
  for (int off = 1; off < 256; off <<= 1) {
    int x = sdata[t];
    int y = (t >= off) ? sdata[t - off] : 0;
    __syncthreads();
    sdata[t] = x + y;
    __syncthreads();
  }
  int run = sdata[t] - tsum;  // exclusive prefix of this thread's chunk
#pragma unroll
  for (int j = 0; j < 4; j++) {
    int idx = base + j;
    if (idx < N_NODES) offs[idx] = run;
    run += v[j];
  }
  if (t == 255) blockSums[b] = sdata[255];
}

// ---------------- K3: scan the 98 block sums (one block) ----------------
__global__ void k_scan2(int* __restrict__ blockSums) {
  __shared__ int sdata[128];
  int t = threadIdx.x;
  int v = (t < SCAN_BLOCKS) ? blockSums[t] : 0;
  sdata[t] = v;
  __syncthreads();
  for (int off = 1; off < 128; off <<= 1) {
    int x = sdata[t];
    int y = (t >= off) ? sdata[t - off] : 0;
    __syncthreads();
    sdata[t] = x + y;
    __syncthreads();
  }
  if (t < SCAN_BLOCKS) blockSums[t] = sdata[t] - v;  // exclusive
}

// ------- K4: finalize offsets, init cursors, compute D^-1/2 norms -------
__global__ void k_finalize(const int* __restrict__ deg_out, const int* __restrict__ deg_in,
                           const int* __restrict__ blockSums,
                           int* __restrict__ offs, int* __restrict__ cursor,
                           float* __restrict__ norm_src, float* __restrict__ norm_dst) {
  int i = blockIdx.x * blockDim.x + threadIdx.x;
  if (i >= N_NODES) return;
  int o = offs[i] + blockSums[i / SCAN_CHUNK];
  offs[i] = o;
  cursor[i] = o;
  norm_src[i] = rsqrtf((float)deg_out[i] + 1.0f);  // self-loop adds +1
  norm_dst[i] = rsqrtf((float)deg_in[i] + 1.0f);
}

// ------------- K5: XCD-partitioned scatter into CSR buckets -------------
// R3 post-mortem: naive scatter = random 4B writes over a 6.4MB window ->
// every write dirties+evicts a 64B line -> WRITE_SIZE 107MB, 131us.
// Fix: partition dst into 8 regions of 12500 nodes (CSR window ~800KB, fits
// one XCD's 4MB L2). Blocks with blockIdx&7==r handle region r; with the
// round-robin block->XCD mapping each region's window stays resident in one
// L2 and lines accumulate all 16 writes before write-back (~6.4MB total).
// dst[] is re-read 8x but is L3-resident. Correct under ANY block mapping.
#define SC_SLICES 256
#define SC_CHUNK (N_EDGES / SC_SLICES)  // 6250
#define SC_REGION (N_NODES / 8)         // 12500
__global__ __launch_bounds__(256) void k_scatter(
    const int* __restrict__ src, const int* __restrict__ dst,
    int* __restrict__ cursor, int* __restrict__ edge_src) {
  int slice = blockIdx.x >> 3;
  int region = blockIdx.x & 7;
  int base = slice * SC_CHUNK;
  for (int i = threadIdx.x; i < SC_CHUNK; i += 256) {
    int e = base + i;
    int d = dst[e];
    if (d / SC_REGION == region) {
      int pos = atomicAdd(&cursor[d], 1);
      edge_src[pos] = src[e];
    }
  }
}

// --------- K6: pull-aggregate. One wave per node, float2 per lane ---------
// agg[v] = norm_dst[v] * ( x[v]*norm_src[v] + sum_{u->v} x[u]*norm_src[u] )
// Unroll 4: the per-edge chain (u -> norm_src[u] -> x[u]) allows only one
// outstanding gather per wave; 4 independent chains hide L2/L3 latency.
__global__ __launch_bounds__(256) void k_aggregate(
    const float* __restrict__ x, const int* __restrict__ edge_src,
    const int* __restrict__ offs, const int* __restrict__ deg_in,
    const float* __restrict__ norm_src, const float* __restrict__ norm_dst,
    float* __restrict__ agg) {
  int wave = (blockIdx.x * blockDim.x + threadIdx.x) >> 6;
  int lane = threadIdx.x & 63;
  if (wave >= N_NODES) return;
  int v = wave;
  float2 a = ((const float2*)(x + (size_t)v * IN_DIM))[lane];
  float ns = norm_src[v];
  float accx = a.x * ns, accy = a.y * ns;
  int beg = offs[v];
  int deg = deg_in[v];
  int e = beg;
  int end4 = beg + (deg & ~3);
  for (; e < end4; e += 4) {
    int u0 = edge_src[e + 0];
    int u1 = edge_src[e + 1];
    int u2 = edge_src[e + 2];
    int u3 = edge_src[e + 3];
    float n0 = norm_src[u0], n1 = norm_src[u1], n2 = norm_src[u2], n3 = norm_src[u3];
    float2 x0 = ((const float2*)(x + (size_t)u0 * IN_DIM))[lane];
    float2 x1 = ((const float2*)(x + (size_t)u1 * IN_DIM))[lane];
    float2 x2 = ((const float2*)(x + (size_t)u2 * IN_DIM))[lane];
    float2 x3 = ((const float2*)(x + (size_t)u3 * IN_DIM))[lane];
    accx += x0.x * n0 + x1.x * n1 + x2.x * n2 + x3.x * n3;
    accy += x0.y * n0 + x1.y * n1 + x2.y * n2 + x3.y * n3;
  }
  int end = beg + deg;
  for (; e < end; e++) {
    int u = edge_src[e];
    float nu = norm_src[u];
    float2 xu = ((const float2*)(x + (size_t)u * IN_DIM))[lane];
    accx += xu.x * nu;
    accy += xu.y * nu;
  }
  float nd = norm_dst[v];
  float2 outv;
  outv.x = accx * nd;
  outv.y = accy * nd;
  ((float2*)(agg + (size_t)v * IN_DIM))[lane] = outv;
}

// ------ K7: f32 GEMM 128x128 tile, 8x8 micro, BK=32 + bias + ReLU + pool ------
// R2 post-mortem: 4x4 micro = 2 B LDS per FMA -> LDS-BW-bound, VALUBusy 25%.
// 8x8 micro (split 4+4 at stride 64, keeping the conflict-free tx*4 b128
// pattern) = 1 B/FMA -> LDS ~ VALU balance. A staged k-major (transpose) so
// A-frags are b128 too. Pool: shfl+LDS block reduction, then 1 atomic/col/graph
// (R2: 6.4M atomics = 100 MB HBM writes; now ~0.2M).
#define BM 128
#define BN 128
#define BK 32
#define LDT 132  // padded leading dim for As/Bs (132%4==0 keeps b128 alignment)

__global__ __launch_bounds__(256, 4) void k_gemm_pool(
    const float* __restrict__ agg, const float* __restrict__ W,
    const float* __restrict__ bias, const int* __restrict__ graph_ids,
    float* __restrict__ hg) {
  __shared__ float As[BK][LDT];  // k-major: As[k][row], 16.9 KB
  __shared__ float Bs[BK][LDT];  // Bs[k][col], 16.9 KB
  __shared__ float red[4][BN];   // pooling cross-wave reduce, 2 KB

  int r0 = blockIdx.x * BM;
  int c0 = blockIdx.y * BN;
  int t = threadIdx.x;
  int tx = t & 15;   // col group
  int ty = t >> 4;   // row group

  float acc[8][8];
#pragma unroll
  for (int i = 0; i < 8; i++)
#pragma unroll
    for (int j = 0; j < 8; j++) acc[i][j] = 0.f;

  for (int kp = 0; kp < IN_DIM; kp += BK) {
    // stage A with transpose: 128 rows x 32 k -> As[k][row]
    {
      int kq = (t & 7) << 2;  // 0,4,..,28
      int row = t >> 3;       // 0..31
#pragma unroll
      for (int it = 0; it < 4; it++) {
        int rl = row + it * 32;
        int grow = r0 + rl;
        int srow = grow < N_NODES ? grow : N_NODES - 1;  // clamp; pool guards
        float4 vv = *(const float4*)&agg[(size_t)srow * IN_DIM + kp + kq];
        As[kq + 0][rl] = vv.x;
        As[kq + 1][rl] = vv.y;
        As[kq + 2][rl] = vv.z;
        As[kq + 3][rl] = vv.w;
      }
    }
    // stage B: 32 k x 128 cols (row-major, direct)
    {
      int cc = (t & 31) << 2;  // 0..124
      int kk = t >> 5;         // 0..7
#pragma unroll
      for (int it = 0; it < 4; it++) {
        int kl = kk + it * 8;
        float4 vv = *(const float4*)&W[(size_t)(kp + kl) * HID + c0 + cc];
        *(float4*)&Bs[kl][cc] = vv;
      }
    }
    __syncthreads();

#pragma unroll 2
    for (int kk = 0; kk < BK; kk++) {
      float4 a0 = *(float4*)&As[kk][ty * 4];
      float4 a1 = *(float4*)&As[kk][64 + ty * 4];
      float4 b0 = *(float4*)&Bs[kk][tx * 4];
      float4 b1 = *(float4*)&Bs[kk][64 + tx * 4];
      float av[8] = {a0.x, a0.y, a0.z, a0.w, a1.x, a1.y, a1.z, a1.w};
      float bv[8] = {b0.x, b0.y, b0.z, b0.w, b1.x, b1.y, b1.z, b1.w};
#pragma unroll
      for (int i = 0; i < 8; i++)
#pragma unroll
        for (int j = 0; j < 8; j++) acc[i][j] += av[i] * bv[j];
    }
    __syncthreads();
  }

  // ---- epilogue: bias + relu in place ----
  float bias_v[8];
#pragma unroll
  for (int j = 0; j < 8; j++) {
    int c = c0 + ((j < 4) ? (tx * 4 + j) : (64 + tx * 4 + j - 4));
    bias_v[j] = bias[c];
  }
  int gid[8];
#pragma unroll
  for (int i = 0; i < 8; i++) {
    int r = r0 + ((i < 4) ? (ty * 4 + i) : (64 + ty * 4 + i - 4));
    gid[i] = (r < N_NODES) ? graph_ids[r] : -1;
  }
#pragma unroll
  for (int i = 0; i < 8; i++)
#pragma unroll
    for (int j = 0; j < 8; j++) acc[i][j] = fmaxf(acc[i][j] + bias_v[j], 0.f);

  // ---- fused max-pool: per-graph block reduction, then 1 atomic/col ----
  // graph_ids sorted -> block spans [gmin, gmax], nearly always <= 2 graphs
  int gmin = graph_ids[r0];
  int rlast = r0 + BM - 1;
  if (rlast >= N_NODES) rlast = N_NODES - 1;
  int gmax = graph_ids[rlast];
  int w = t >> 6;  // wave id 0..3

  for (int g = gmin; g <= gmax; g++) {
    float m[8];
#pragma unroll
    for (int j = 0; j < 8; j++) m[j] = 0.f;  // relu output >= 0, so 0 is identity
#pragma unroll
    for (int i = 0; i < 8; i++) {
      if (gid[i] == g) {
#pragma unroll
        for (int j = 0; j < 8; j++) m[j] = fmaxf(m[j], acc[i][j]);
      }
    }
    // reduce across the 4 ty values within the wave (lanes ^16, ^32)
#pragma unroll
    for (int j = 0; j < 8; j++) {
      m[j] = fmaxf(m[j], __shfl_xor(m[j], 16, 64));
      m[j] = fmaxf(m[j], __shfl_xor(m[j], 32, 64));
    }
    if ((t & 63) < 16) {
#pragma unroll
      for (int j = 0; j < 8; j++) {
        int cl = (j < 4) ? (tx * 4 + j) : (64 + tx * 4 + j - 4);
        red[w][cl] = m[j];
      }
    }
    __syncthreads();
    if (t < BN) {
      float mm = fmaxf(fmaxf(red[0][t], red[1][t]), fmaxf(red[2][t], red[3][t]));
      atomicMax((unsigned int*)&hg[g * HID + c0 + t], __float_as_uint(mm));
    }
    __syncthreads();
  }
}

// ---------- K8: tiny classifier GEMM + log_softmax. 1 block, 64 thr ----------
__global__ void k_classify(const float* __restrict__ hg, const float* __restrict__ Wc,
                           const float* __restrict__ bc, float* __restrict__ out) {
  int g = threadIdx.x;
  if (g >= N_GRAPHS) return;
  float logits[NCLS];
#pragma unroll
  for (int c = 0; c < NCLS; c++) logits[c] = bc[c];
  for (int k = 0; k < HID; k++) {
    float h = hg[g * HID + k];
#pragma unroll
    for (int c = 0; c < NCLS; c++) logits[c] += h * Wc[k * NCLS + c];
  }
  float m = logits[0];
#pragma unroll
  for (int c = 1; c < NCLS; c++) m = fmaxf(m, logits[c]);
  float s = 0.f;
#pragma unroll
  for (int c = 0; c < NCLS; c++) s += expf(logits[c] - m);
  float lse = logf(s) + m;
#pragma unroll
  for (int c = 0; c < NCLS; c++) out[g * NCLS + c] = logits[c] - lse;
}

extern "C" void kernel_launch(void* const* d_in, const int* in_sizes, int n_in,
                              void* d_out, int out_size, void* d_ws, size_t ws_size,
                              hipStream_t stream) {
  const float* x = (const float*)d_in[0];
  const int* src = (const int*)d_in[1];
  const int* dst = (const int*)d_in[2];
  const int* graph_ids = (const int*)d_in[3];
  const float* W = (const float*)d_in[4];
  const float* b = (const float*)d_in[5];
  const float* Wc = (const float*)d_in[6];
  const float* bc = (const float*)d_in[7];
  float* out = (float*)d_out;

  // ---- workspace layout (~60 MB total) ----
  int* deg_out = (int*)d_ws;                  // 100000
  int* deg_in = deg_out + N_NODES;            // 100000
  float* hg = (float*)(deg_in + N_NODES);     // 64*256 = 16384
  float* norm_src = hg + N_GRAPHS * HID;      // 100000
  float* norm_dst = norm_src + N_NODES;       // 100000
  int* offs = (int*)(norm_dst + N_NODES);     // 100000
  int* cursor = offs + N_NODES;               // 100000
  int* blockSums = cursor + N_NODES;          // 128
  int* edge_src = blockSums + 128;            // 1600000
  float* agg = (float*)(edge_src + N_EDGES);  // 100000*128

  // zero deg_out, deg_in, hg (contiguous prefix of ws)
  size_t zbytes = (size_t)(2 * N_NODES + N_GRAPHS * HID) * 4;
  hipMemsetAsync(d_ws, 0, zbytes, stream);

  k_degrees<<<2048, 256, 0, stream>>>(src, dst, deg_out, deg_in);
  k_scan1<<<SCAN_BLOCKS, 256, 0, stream>>>(deg_in, offs, blockSums);
  k_scan2<<<1, 128, 0, stream>>>(blockSums);
  k_finalize<<<(N_NODES + 255) / 256, 256, 0, stream>>>(deg_out, deg_in, blockSums,
                                                        offs, cursor, norm_src, norm_dst);
  k_scatter<<<2048, 256, 0, stream>>>(src, dst, cursor, edge_src);
  k_aggregate<<<N_NODES / 4, 256, 0, stream>>>(x, edge_src, offs, deg_in,
                                               norm_src, norm_dst, agg);
  dim3 ggrid((N_NODES + BM - 1) / BM, HID / BN);
  k_gemm_pool<<<ggrid, 256, 0, stream>>>(agg, W, b, graph_ids, hg);
  k_classify<<<1, 64, 0, stream>>>(hg, Wc, bc, out);
}

// Round 6
// 506.875 us; speedup vs baseline: 8.5364x; 1.0465x over previous
//
#include <hip/hip_runtime.h>
#include <hip/hip_bf16.h>
#include <math.h>

#define N_NODES 100000
#define N_EDGES 1600000
#define N_GRAPHS 64
#define IN_DIM 128
#define HID 256
#define NCLS 16

#define SCAN_CHUNK 1024
#define SCAN_BLOCKS ((N_NODES + SCAN_CHUNK - 1) / SCAN_CHUNK)  // 98

// ---------------- K1: degree count (int atomics, cheap) ----------------
__global__ void k_degrees(const int* __restrict__ src, const int* __restrict__ dst,
                          int* __restrict__ deg_out, int* __restrict__ deg_in) {
  int i = blockIdx.x * blockDim.x + threadIdx.x;
  int stride = gridDim.x * blockDim.x;
  for (; i < N_EDGES; i += stride) {
    atomicAdd(&deg_out[src[i]], 1);
    atomicAdd(&deg_in[dst[i]], 1);
  }
}

// ---------------- K2: per-chunk exclusive scan of deg_in ----------------
__global__ void k_scan1(const int* __restrict__ deg_in, int* __restrict__ offs,
                        int* __restrict__ blockSums) {
  __shared__ int sdata[256];
  int b = blockIdx.x, t = threadIdx.x;
  int base = b * SCAN_CHUNK + t * 4;
  int v[4];
#pragma unroll
  for (int j = 0; j < 4; j++) {
    int idx = base + j;
    v[j] = (idx < N_NODES) ? deg_in[idx] : 0;
  }
  int tsum = v[0] + v[1] + v[2] + v[3];
  sdata[t] = tsum;
  __syncthreads();
  for (int off = 1; off < 256; off <<= 1) {
    int x = sdata[t];
    int y = (t >= off) ? sdata[t - off] : 0;
    __syncthreads();
    sdata[t] = x + y;
    __syncthreads();
  }
  int run = sdata[t] - tsum;  // exclusive prefix of this thread's chunk
#pragma unroll
  for (int j = 0; j < 4; j++) {
    int idx = base + j;
    if (idx < N_NODES) offs[idx] = run;
    run += v[j];
  }
  if (t == 255) blockSums[b] = sdata[255];
}

// ---------------- K3: scan the 98 block sums (one block) ----------------
__global__ void k_scan2(int* __restrict__ blockSums) {
  __shared__ int sdata[128];
  int t = threadIdx.x;
  int v = (t < SCAN_BLOCKS) ? blockSums[t] : 0;
  sdata[t] = v;
  __syncthreads();
  for (int off = 1; off < 128; off <<= 1) {
    int x = sdata[t];
    int y = (t >= off) ? sdata[t - off] : 0;
    __syncthreads();
    sdata[t] = x + y;
    __syncthreads();
  }
  if (t < SCAN_BLOCKS) blockSums[t] = sdata[t] - v;  // exclusive
}

// ------- K4: finalize offsets, init cursors, compute D^-1/2 norms -------
__global__ void k_finalize(const int* __restrict__ deg_out, const int* __restrict__ deg_in,
                           const int* __restrict__ blockSums,
                           int* __restrict__ offs, int* __restrict__ cursor,
                           float* __restrict__ norm_src, float* __restrict__ norm_dst) {
  int i = blockIdx.x * blockDim.x + threadIdx.x;
  if (i >= N_NODES) return;
  int o = offs[i] + blockSums[i / SCAN_CHUNK];
  offs[i] = o;
  cursor[i] = o;
  norm_src[i] = rsqrtf((float)deg_out[i] + 1.0f);  // self-loop adds +1
  norm_dst[i] = rsqrtf((float)deg_in[i] + 1.0f);
}

// ------ K4b: premultiply xs = x * norm_src, stored bf16 (R4) ------
// R4 post-mortem: k_aggregate is BW-bound on the L2-miss path (419MB FETCH,
// 3.75 TB/s, plenty of MLP in flight). Only lever at a BW roofline: bytes.
// bf16 halves the gathered row (512B -> 256B) and folds norm_src in, deleting
// the per-edge norm gather. Accumulation stays f32.
__global__ void k_premul(const float* __restrict__ x, const float* __restrict__ norm_src,
                         __hip_bfloat162* __restrict__ xs) {
  int i = blockIdx.x * blockDim.x + threadIdx.x;  // one float2 per thread
  if (i >= N_NODES * (IN_DIM / 2)) return;
  int v = i >> 6;  // IN_DIM/2 == 64 pairs per node
  float ns = norm_src[v];
  float2 a = ((const float2*)x)[i];
  __hip_bfloat162 o;
  o.x = __float2bfloat16(a.x * ns);
  o.y = __float2bfloat16(a.y * ns);
  xs[i] = o;
}

// ------------- K5: XCD-partitioned scatter into CSR buckets -------------
// R3 post-mortem: naive scatter = random 4B writes over a 6.4MB window ->
// every write dirties+evicts a 64B line -> WRITE_SIZE 107MB, 131us.
// Fix: partition dst into 8 regions of 12500 nodes (CSR window ~800KB, fits
// one XCD's 4MB L2). Blocks with blockIdx&7==r handle region r.
#define SC_SLICES 256
#define SC_CHUNK (N_EDGES / SC_SLICES)  // 6250
#define SC_REGION (N_NODES / 8)         // 12500
__global__ __launch_bounds__(256) void k_scatter(
    const int* __restrict__ src, const int* __restrict__ dst,
    int* __restrict__ cursor, int* __restrict__ edge_src) {
  int slice = blockIdx.x >> 3;
  int region = blockIdx.x & 7;
  int base = slice * SC_CHUNK;
  for (int i = threadIdx.x; i < SC_CHUNK; i += 256) {
    int e = base + i;
    int d = dst[e];
    if (d / SC_REGION == region) {
      int pos = atomicAdd(&cursor[d], 1);
      edge_src[pos] = src[e];
    }
  }
}

// --------- K6: pull-aggregate from bf16 xs. One wave per node ---------
// agg[v] = norm_dst[v] * ( xs[v] + sum_{u->v} xs[u] ), xs already has norm_src.
// Unroll 8: 256B rows (bf16) halve in-flight bytes vs f32; 8 chains restore MLP.
__global__ __launch_bounds__(256) void k_aggregate(
    const __hip_bfloat162* __restrict__ xs, const int* __restrict__ edge_src,
    const int* __restrict__ offs, const int* __restrict__ deg_in,
    const float* __restrict__ norm_dst, float* __restrict__ agg) {
  int wave = (blockIdx.x * blockDim.x + threadIdx.x) >> 6;
  int lane = threadIdx.x & 63;
  if (wave >= N_NODES) return;
  int v = wave;
  __hip_bfloat162 a = xs[(size_t)v * 64 + lane];
  float accx = __bfloat162float(a.x), accy = __bfloat162float(a.y);
  int beg = offs[v];
  int deg = deg_in[v];
  int e = beg;
  int end8 = beg + (deg & ~7);
  for (; e < end8; e += 8) {
    int u0 = edge_src[e + 0], u1 = edge_src[e + 1];
    int u2 = edge_src[e + 2], u3 = edge_src[e + 3];
    int u4 = edge_src[e + 4], u5 = edge_src[e + 5];
    int u6 = edge_src[e + 6], u7 = edge_src[e + 7];
    __hip_bfloat162 x0 = xs[(size_t)u0 * 64 + lane];
    __hip_bfloat162 x1 = xs[(size_t)u1 * 64 + lane];
    __hip_bfloat162 x2 = xs[(size_t)u2 * 64 + lane];
    __hip_bfloat162 x3 = xs[(size_t)u3 * 64 + lane];
    __hip_bfloat162 x4 = xs[(size_t)u4 * 64 + lane];
    __hip_bfloat162 x5 = xs[(size_t)u5 * 64 + lane];
    __hip_bfloat162 x6 = xs[(size_t)u6 * 64 + lane];
    __hip_bfloat162 x7 = xs[(size_t)u7 * 64 + lane];
    accx += __bfloat162float(x0.x) + __bfloat162float(x1.x) +
            __bfloat162float(x2.x) + __bfloat162float(x3.x) +
            __bfloat162float(x4.x) + __bfloat162float(x5.x) +
            __bfloat162float(x6.x) + __bfloat162float(x7.x);
    accy += __bfloat162float(x0.y) + __bfloat162float(x1.y) +
            __bfloat162float(x2.y) + __bfloat162float(x3.y) +
            __bfloat162float(x4.y) + __bfloat162float(x5.y) +
            __bfloat162float(x6.y) + __bfloat162float(x7.y);
  }
  int end = beg + deg;
  for (; e < end; e++) {
    int u = edge_src[e];
    __hip_bfloat162 xu = xs[(size_t)u * 64 + lane];
    accx += __bfloat162float(xu.x);
    accy += __bfloat162float(xu.y);
  }
  float nd = norm_dst[v];
  float2 outv;
  outv.x = accx * nd;
  outv.y = accy * nd;
  ((float2*)(agg + (size_t)v * IN_DIM))[lane] = outv;
}

// -------- K6f: f32 fallback aggregate (used only if ws too small) --------
__global__ __launch_bounds__(256) void k_aggregate_f32(
    const float* __restrict__ x, const int* __restrict__ edge_src,
    const int* __restrict__ offs, const int* __restrict__ deg_in,
    const float* __restrict__ norm_src, const float* __restrict__ norm_dst,
    float* __restrict__ agg) {
  int wave = (blockIdx.x * blockDim.x + threadIdx.x) >> 6;
  int lane = threadIdx.x & 63;
  if (wave >= N_NODES) return;
  int v = wave;
  float2 a = ((const float2*)(x + (size_t)v * IN_DIM))[lane];
  float ns = norm_src[v];
  float accx = a.x * ns, accy = a.y * ns;
  int beg = offs[v];
  int deg = deg_in[v];
  for (int e = beg; e < beg + deg; e++) {
    int u = edge_src[e];
    float nu = norm_src[u];
    float2 xu = ((const float2*)(x + (size_t)u * IN_DIM))[lane];
    accx += xu.x * nu;
    accy += xu.y * nu;
  }
  float nd = norm_dst[v];
  float2 outv;
  outv.x = accx * nd;
  outv.y = accy * nd;
  ((float2*)(agg + (size_t)v * IN_DIM))[lane] = outv;
}

// ------ K7: f32 GEMM 128x128 tile, 8x8 micro, BK=32 + bias + ReLU + pool ------
#define BM 128
#define BN 128
#define BK 32
#define LDT 132  // padded leading dim for As/Bs (132%4==0 keeps b128 alignment)

__global__ __launch_bounds__(256, 4) void k_gemm_pool(
    const float* __restrict__ agg, const float* __restrict__ W,
    const float* __restrict__ bias, const int* __restrict__ graph_ids,
    float* __restrict__ hg) {
  __shared__ float As[BK][LDT];  // k-major: As[k][row], 16.9 KB
  __shared__ float Bs[BK][LDT];  // Bs[k][col], 16.9 KB
  __shared__ float red[4][BN];   // pooling cross-wave reduce, 2 KB

  int r0 = blockIdx.x * BM;
  int c0 = blockIdx.y * BN;
  int t = threadIdx.x;
  int tx = t & 15;   // col group
  int ty = t >> 4;   // row group

  float acc[8][8];
#pragma unroll
  for (int i = 0; i < 8; i++)
#pragma unroll
    for (int j = 0; j < 8; j++) acc[i][j] = 0.f;

  for (int kp = 0; kp < IN_DIM; kp += BK) {
    // stage A with transpose: 128 rows x 32 k -> As[k][row]
    {
      int kq = (t & 7) << 2;  // 0,4,..,28
      int row = t >> 3;       // 0..31
#pragma unroll
      for (int it = 0; it < 4; it++) {
        int rl = row + it * 32;
        int grow = r0 + rl;
        int srow = grow < N_NODES ? grow : N_NODES - 1;  // clamp; pool guards
        float4 vv = *(const float4*)&agg[(size_t)srow * IN_DIM + kp + kq];
        As[kq + 0][rl] = vv.x;
        As[kq + 1][rl] = vv.y;
        As[kq + 2][rl] = vv.z;
        As[kq + 3][rl] = vv.w;
      }
    }
    // stage B: 32 k x 128 cols (row-major, direct)
    {
      int cc = (t & 31) << 2;  // 0..124
      int kk = t >> 5;         // 0..7
#pragma unroll
      for (int it = 0; it < 4; it++) {
        int kl = kk + it * 8;
        float4 vv = *(const float4*)&W[(size_t)(kp + kl) * HID + c0 + cc];
        *(float4*)&Bs[kl][cc] = vv;
      }
    }
    __syncthreads();

#pragma unroll 2
    for (int kk = 0; kk < BK; kk++) {
      float4 a0 = *(float4*)&As[kk][ty * 4];
      float4 a1 = *(float4*)&As[kk][64 + ty * 4];
      float4 b0 = *(float4*)&Bs[kk][tx * 4];
      float4 b1 = *(float4*)&Bs[kk][64 + tx * 4];
      float av[8] = {a0.x, a0.y, a0.z, a0.w, a1.x, a1.y, a1.z, a1.w};
      float bv[8] = {b0.x, b0.y, b0.z, b0.w, b1.x, b1.y, b1.z, b1.w};
#pragma unroll
      for (int i = 0; i < 8; i++)
#pragma unroll
        for (int j = 0; j < 8; j++) acc[i][j] += av[i] * bv[j];
    }
    __syncthreads();
  }

  // ---- epilogue: bias + relu in place ----
  float bias_v[8];
#pragma unroll
  for (int j = 0; j < 8; j++) {
    int c = c0 + ((j < 4) ? (tx * 4 + j) : (64 + tx * 4 + j - 4));
    bias_v[j] = bias[c];
  }
  int gid[8];
#pragma unroll
  for (int i = 0; i < 8; i++) {
    int r = r0 + ((i < 4) ? (ty * 4 + i) : (64 + ty * 4 + i - 4));
    gid[i] = (r < N_NODES) ? graph_ids[r] : -1;
  }
#pragma unroll
  for (int i = 0; i < 8; i++)
#pragma unroll
    for (int j = 0; j < 8; j++) acc[i][j] = fmaxf(acc[i][j] + bias_v[j], 0.f);

  // ---- fused max-pool: per-graph block reduction, then 1 atomic/col ----
  int gmin = graph_ids[r0];
  int rlast = r0 + BM - 1;
  if (rlast >= N_NODES) rlast = N_NODES - 1;
  int gmax = graph_ids[rlast];
  int w = t >> 6;  // wave id 0..3

  for (int g = gmin; g <= gmax; g++) {
    float m[8];
#pragma unroll
    for (int j = 0; j < 8; j++) m[j] = 0.f;  // relu output >= 0, so 0 is identity
#pragma unroll
    for (int i = 0; i < 8; i++) {
      if (gid[i] == g) {
#pragma unroll
        for (int j = 0; j < 8; j++) m[j] = fmaxf(m[j], acc[i][j]);
      }
    }
#pragma unroll
    for (int j = 0; j < 8; j++) {
      m[j] = fmaxf(m[j], __shfl_xor(m[j], 16, 64));
      m[j] = fmaxf(m[j], __shfl_xor(m[j], 32, 64));
    }
    if ((t & 63) < 16) {
#pragma unroll
      for (int j = 0; j < 8; j++) {
        int cl = (j < 4) ? (tx * 4 + j) : (64 + tx * 4 + j - 4);
        red[w][cl] = m[j];
      }
    }
    __syncthreads();
    if (t < BN) {
      float mm = fmaxf(fmaxf(red[0][t], red[1][t]), fmaxf(red[2][t], red[3][t]));
      atomicMax((unsigned int*)&hg[g * HID + c0 + t], __float_as_uint(mm));
    }
    __syncthreads();
  }
}

// ---------- K8: tiny classifier GEMM + log_softmax. 1 block, 64 thr ----------
__global__ void k_classify(const float* __restrict__ hg, const float* __restrict__ Wc,
                           const float* __restrict__ bc, float* __restrict__ out) {
  int g = threadIdx.x;
  if (g >= N_GRAPHS) return;
  float logits[NCLS];
#pragma unroll
  for (int c = 0; c < NCLS; c++) logits[c] = bc[c];
  for (int k = 0; k < HID; k++) {
    float h = hg[g * HID + k];
#pragma unroll
    for (int c = 0; c < NCLS; c++) logits[c] += h * Wc[k * NCLS + c];
  }
  float m = logits[0];
#pragma unroll
  for (int c = 1; c < NCLS; c++) m = fmaxf(m, logits[c]);
  float s = 0.f;
#pragma unroll
  for (int c = 0; c < NCLS; c++) s += expf(logits[c] - m);
  float lse = logf(s) + m;
#pragma unroll
  for (int c = 0; c < NCLS; c++) out[g * NCLS + c] = logits[c] - lse;
}

extern "C" void kernel_launch(void* const* d_in, const int* in_sizes, int n_in,
                              void* d_out, int out_size, void* d_ws, size_t ws_size,
                              hipStream_t stream) {
  const float* x = (const float*)d_in[0];
  const int* src = (const int*)d_in[1];
  const int* dst = (const int*)d_in[2];
  const int* graph_ids = (const int*)d_in[3];
  const float* W = (const float*)d_in[4];
  const float* b = (const float*)d_in[5];
  const float* Wc = (const float*)d_in[6];
  const float* bc = (const float*)d_in[7];
  float* out = (float*)d_out;

  // ---- workspace layout (~86 MB with xs) ----
  int* deg_out = (int*)d_ws;                  // 100000
  int* deg_in = deg_out + N_NODES;            // 100000
  float* hg = (float*)(deg_in + N_NODES);     // 64*256 = 16384
  float* norm_src = hg + N_GRAPHS * HID;      // 100000
  float* norm_dst = norm_src + N_NODES;       // 100000
  int* offs = (int*)(norm_dst + N_NODES);     // 100000
  int* cursor = offs + N_NODES;               // 100000
  int* blockSums = cursor + N_NODES;          // 128
  int* edge_src = blockSums + 128;            // 1600000
  float* agg = (float*)(edge_src + N_EDGES);  // 100000*128 f32
  __hip_bfloat162* xs = (__hip_bfloat162*)(agg + (size_t)N_NODES * IN_DIM);  // 100000*64
  size_t need = (char*)(xs + (size_t)N_NODES * (IN_DIM / 2)) - (char*)d_ws;
  bool use_bf16 = ws_size >= need;

  // zero deg_out, deg_in, hg (contiguous prefix of ws)
  size_t zbytes = (size_t)(2 * N_NODES + N_GRAPHS * HID) * 4;
  hipMemsetAsync(d_ws, 0, zbytes, stream);

  k_degrees<<<2048, 256, 0, stream>>>(src, dst, deg_out, deg_in);
  k_scan1<<<SCAN_BLOCKS, 256, 0, stream>>>(deg_in, offs, blockSums);
  k_scan2<<<1, 128, 0, stream>>>(blockSums);
  k_finalize<<<(N_NODES + 255) / 256, 256, 0, stream>>>(deg_out, deg_in, blockSums,
                                                        offs, cursor, norm_src, norm_dst);
  if (use_bf16)
    k_premul<<<(N_NODES * (IN_DIM / 2) + 255) / 256, 256, 0, stream>>>(x, norm_src, xs);
  k_scatter<<<2048, 256, 0, stream>>>(src, dst, cursor, edge_src);
  if (use_bf16)
    k_aggregate<<<N_NODES / 4, 256, 0, stream>>>(xs, edge_src, offs, deg_in,
                                                 norm_dst, agg);
  else
    k_aggregate_f32<<<N_NODES / 4, 256, 0, stream>>>(x, edge_src, offs, deg_in,
                                                     norm_src, norm_dst, agg);
  dim3 ggrid((N_NODES + BM - 1) / BM, HID / BN);
  k_gemm_pool<<<ggrid, 256, 0, stream>>>(agg, W, b, graph_ids, hg);
  k_classify<<<1, 64, 0, stream>>>(hg, Wc, bc, out);
}

// Round 7
// 411.181 us; speedup vs baseline: 10.5230x; 1.2327x over previous
//
#include <hip/hip_runtime.h>
#include <hip/hip_bf16.h>
#include <math.h>

#define N_NODES 100000
#define N_EDGES 1600000
#define N_GRAPHS 64
#define IN_DIM 128
#define HID 256
#define NCLS 16

#define SCAN_CHUNK 1024
#define SCAN_BLOCKS ((N_NODES + SCAN_CHUNK - 1) / SCAN_CHUNK)  // 98

// ---- K1: degree count via LDS-privatized histograms (R6) ----
// R6 post-mortem: global atomicAdd degree count = 3.2M device-scope RMWs
// executing past L2 (per-XCD L2 non-coherent) -> 99.8MB WRITE_SIZE, 124us,
// atomic-rate-bound. Fix: zero global atomics. 8 node-regions x 50KB LDS
// histograms; 32 edge-slices; plain coalesced scratch writes + tree reduce.
#define NREG 8
#define REGSZ (N_NODES / NREG)    // 12500
#define NSLC 32
#define SLICE (N_EDGES / NSLC)    // 50000

__global__ __launch_bounds__(256) void k_deghist(
    const int* __restrict__ src, const int* __restrict__ dst,
    int* __restrict__ scratch) {
  __shared__ int hist[REGSZ];  // 50 KB
  int slice = blockIdx.x, region = blockIdx.y, z = blockIdx.z;
  const int* arr = z ? src : dst;
  int t = threadIdx.x;
  for (int r = t; r < REGSZ; r += 256) hist[r] = 0;
  __syncthreads();
  int base = region * REGSZ;
  const int4* a4 = (const int4*)(arr + (size_t)slice * SLICE);
  for (int i = t; i < SLICE / 4; i += 256) {
    int4 v = a4[i];
    int d;
    d = v.x - base; if ((unsigned)d < REGSZ) atomicAdd(&hist[d], 1);
    d = v.y - base; if ((unsigned)d < REGSZ) atomicAdd(&hist[d], 1);
    d = v.z - base; if ((unsigned)d < REGSZ) atomicAdd(&hist[d], 1);
    d = v.w - base; if ((unsigned)d < REGSZ) atomicAdd(&hist[d], 1);
  }
  __syncthreads();
  int* outp = scratch + ((size_t)(z * NREG + region) * NSLC + slice) * REGSZ;
  for (int r = t; r < REGSZ; r += 256) outp[r] = hist[r];
}

__global__ void k_degreduce(const int* __restrict__ scratch,
                            int* __restrict__ deg_in, int* __restrict__ deg_out) {
  int i = blockIdx.x * blockDim.x + threadIdx.x;
  if (i >= 2 * N_NODES) return;
  int z = i / N_NODES;
  int node = i - z * N_NODES;
  int region = node / REGSZ;
  int r = node - region * REGSZ;
  const int* p = scratch + (size_t)(z * NREG + region) * NSLC * REGSZ + r;
  int s = 0;
#pragma unroll
  for (int sl = 0; sl < NSLC; sl++) s += p[(size_t)sl * REGSZ];
  if (z == 0) deg_in[node] = s; else deg_out[node] = s;
}

// ---------------- K2: per-chunk exclusive scan of deg_in ----------------
__global__ void k_scan1(const int* __restrict__ deg_in, int* __restrict__ offs,
                        int* __restrict__ blockSums) {
  __shared__ int sdata[256];
  int b = blockIdx.x, t = threadIdx.x;
  int base = b * SCAN_CHUNK + t * 4;
  int v[4];
#pragma unroll
  for (int j = 0; j < 4; j++) {
    int idx = base + j;
    v[j] = (idx < N_NODES) ? deg_in[idx] : 0;
  }
  int tsum = v[0] + v[1] + v[2] + v[3];
  sdata[t] = tsum;
  __syncthreads();
  for (int off = 1; off < 256; off <<= 1) {
    int x = sdata[t];
    int y = (t >= off) ? sdata[t - off] : 0;
    __syncthreads();
    sdata[t] = x + y;
    __syncthreads();
  }
  int run = sdata[t] - tsum;  // exclusive prefix of this thread's chunk
#pragma unroll
  for (int j = 0; j < 4; j++) {
    int idx = base + j;
    if (idx < N_NODES) offs[idx] = run;
    run += v[j];
  }
  if (t == 255) blockSums[b] = sdata[255];
}

// ---------------- K3: scan the 98 block sums (one block) ----------------
__global__ void k_scan2(int* __restrict__ blockSums) {
  __shared__ int sdata[128];
  int t = threadIdx.x;
  int v = (t < SCAN_BLOCKS) ? blockSums[t] : 0;
  sdata[t] = v;
  __syncthreads();
  for (int off = 1; off < 128; off <<= 1) {
    int x = sdata[t];
    int y = (t >= off) ? sdata[t - off] : 0;
    __syncthreads();
    sdata[t] = x + y;
    __syncthreads();
  }
  if (t < SCAN_BLOCKS) blockSums[t] = sdata[t] - v;  // exclusive
}

// ------- K4: finalize offsets, init cursors, compute D^-1/2 norms -------
__global__ void k_finalize(const int* __restrict__ deg_out, const int* __restrict__ deg_in,
                           const int* __restrict__ blockSums,
                           int* __restrict__ offs, int* __restrict__ cursor,
                           float* __restrict__ norm_src, float* __restrict__ norm_dst) {
  int i = blockIdx.x * blockDim.x + threadIdx.x;
  if (i >= N_NODES) return;
  int o = offs[i] + blockSums[i / SCAN_CHUNK];
  offs[i] = o;
  cursor[i] = o;
  norm_src[i] = rsqrtf((float)deg_out[i] + 1.0f);  // self-loop adds +1
  norm_dst[i] = rsqrtf((float)deg_in[i] + 1.0f);
}

// ------ K4b: premultiply xs = x * norm_src, stored bf16 (R4) ------
// R4 post-mortem: k_aggregate is BW-bound on the L2-miss path (419MB FETCH,
// 3.75 TB/s, plenty of MLP in flight). Only lever at a BW roofline: bytes.
// bf16 halves the gathered row (512B -> 256B) and folds norm_src in, deleting
// the per-edge norm gather. Accumulation stays f32. (R6: absmax 0.0156, passes.)
__global__ void k_premul(const float* __restrict__ x, const float* __restrict__ norm_src,
                         __hip_bfloat162* __restrict__ xs) {
  int i = blockIdx.x * blockDim.x + threadIdx.x;  // one float2 per thread
  if (i >= N_NODES * (IN_DIM / 2)) return;
  int v = i >> 6;  // IN_DIM/2 == 64 pairs per node
  float ns = norm_src[v];
  float2 a = ((const float2*)x)[i];
  __hip_bfloat162 o;
  o.x = __float2bfloat16(a.x * ns);
  o.y = __float2bfloat16(a.y * ns);
  xs[i] = o;
}

// ------------- K5: XCD-partitioned scatter into CSR buckets -------------
// R3 post-mortem: naive scatter = random 4B writes over a 6.4MB window ->
// every write dirties+evicts a 64B line -> WRITE_SIZE 107MB, 131us.
// Fix: partition dst into 8 regions of 12500 nodes (CSR window ~800KB, fits
// one XCD's 4MB L2). Blocks with blockIdx&7==r handle region r.
#define SC_SLICES 256
#define SC_CHUNK (N_EDGES / SC_SLICES)  // 6250
#define SC_REGION (N_NODES / 8)         // 12500
__global__ __launch_bounds__(256) void k_scatter(
    const int* __restrict__ src, const int* __restrict__ dst,
    int* __restrict__ cursor, int* __restrict__ edge_src) {
  int slice = blockIdx.x >> 3;
  int region = blockIdx.x & 7;
  int base = slice * SC_CHUNK;
  for (int i = threadIdx.x; i < SC_CHUNK; i += 256) {
    int e = base + i;
    int d = dst[e];
    if (d / SC_REGION == region) {
      int pos = atomicAdd(&cursor[d], 1);
      edge_src[pos] = src[e];
    }
  }
}

// --------- K6: pull-aggregate from bf16 xs. One wave per node ---------
// agg[v] = norm_dst[v] * ( xs[v] + sum_{u->v} xs[u] ), xs already has norm_src.
// Unroll 8: 256B rows (bf16) halve in-flight bytes vs f32; 8 chains restore MLP.
__global__ __launch_bounds__(256) void k_aggregate(
    const __hip_bfloat162* __restrict__ xs, const int* __restrict__ edge_src,
    const int* __restrict__ offs, const int* __restrict__ deg_in,
    const float* __restrict__ norm_dst, float* __restrict__ agg) {
  int wave = (blockIdx.x * blockDim.x + threadIdx.x) >> 6;
  int lane = threadIdx.x & 63;
  if (wave >= N_NODES) return;
  int v = wave;
  __hip_bfloat162 a = xs[(size_t)v * 64 + lane];
  float accx = __bfloat162float(a.x), accy = __bfloat162float(a.y);
  int beg = offs[v];
  int deg = deg_in[v];
  int e = beg;
  int end8 = beg + (deg & ~7);
  for (; e < end8; e += 8) {
    int u0 = edge_src[e + 0], u1 = edge_src[e + 1];
    int u2 = edge_src[e + 2], u3 = edge_src[e + 3];
    int u4 = edge_src[e + 4], u5 = edge_src[e + 5];
    int u6 = edge_src[e + 6], u7 = edge_src[e + 7];
    __hip_bfloat162 x0 = xs[(size_t)u0 * 64 + lane];
    __hip_bfloat162 x1 = xs[(size_t)u1 * 64 + lane];
    __hip_bfloat162 x2 = xs[(size_t)u2 * 64 + lane];
    __hip_bfloat162 x3 = xs[(size_t)u3 * 64 + lane];
    __hip_bfloat162 x4 = xs[(size_t)u4 * 64 + lane];
    __hip_bfloat162 x5 = xs[(size_t)u5 * 64 + lane];
    __hip_bfloat162 x6 = xs[(size_t)u6 * 64 + lane];
    __hip_bfloat162 x7 = xs[(size_t)u7 * 64 + lane];
    accx += __bfloat162float(x0.x) + __bfloat162float(x1.x) +
            __bfloat162float(x2.x) + __bfloat162float(x3.x) +
            __bfloat162float(x4.x) + __bfloat162float(x5.x) +
            __bfloat162float(x6.x) + __bfloat162float(x7.x);
    accy += __bfloat162float(x0.y) + __bfloat162float(x1.y) +
            __bfloat162float(x2.y) + __bfloat162float(x3.y) +
            __bfloat162float(x4.y) + __bfloat162float(x5.y) +
            __bfloat162float(x6.y) + __bfloat162float(x7.y);
  }
  int end = beg + deg;
  for (; e < end; e++) {
    int u = edge_src[e];
    __hip_bfloat162 xu = xs[(size_t)u * 64 + lane];
    accx += __bfloat162float(xu.x);
    accy += __bfloat162float(xu.y);
  }
  float nd = norm_dst[v];
  float2 outv;
  outv.x = accx * nd;
  outv.y = accy * nd;
  ((float2*)(agg + (size_t)v * IN_DIM))[lane] = outv;
}

// -------- K6f: f32 fallback aggregate (used only if ws too small) --------
__global__ __launch_bounds__(256) void k_aggregate_f32(
    const float* __restrict__ x, const int* __restrict__ edge_src,
    const int* __restrict__ offs, const int* __restrict__ deg_in,
    const float* __restrict__ norm_src, const float* __restrict__ norm_dst,
    float* __restrict__ agg) {
  int wave = (blockIdx.x * blockDim.x + threadIdx.x) >> 6;
  int lane = threadIdx.x & 63;
  if (wave >= N_NODES) return;
  int v = wave;
  float2 a = ((const float2*)(x + (size_t)v * IN_DIM))[lane];
  float ns = norm_src[v];
  float accx = a.x * ns, accy = a.y * ns;
  int beg = offs[v];
  int deg = deg_in[v];
  for (int e = beg; e < beg + deg; e++) {
    int u = edge_src[e];
    float nu = norm_src[u];
    float2 xu = ((const float2*)(x + (size_t)u * IN_DIM))[lane];
    accx += xu.x * nu;
    accy += xu.y * nu;
  }
  float nd = norm_dst[v];
  float2 outv;
  outv.x = accx * nd;
  outv.y = accy * nd;
  ((float2*)(agg + (size_t)v * IN_DIM))[lane] = outv;
}

// ------ K7: f32 GEMM 128x128 tile, 8x8 micro, BK=32 + bias + ReLU + pool ------
#define BM 128
#define BN 128
#define BK 32
#define LDT 132  // padded leading dim for As/Bs (132%4==0 keeps b128 alignment)

__global__ __launch_bounds__(256, 4) void k_gemm_pool(
    const float* __restrict__ agg, const float* __restrict__ W,
    const float* __restrict__ bias, const int* __restrict__ graph_ids,
    float* __restrict__ hg) {
  __shared__ float As[BK][LDT];  // k-major: As[k][row], 16.9 KB
  __shared__ float Bs[BK][LDT];  // Bs[k][col], 16.9 KB
  __shared__ float red[4][BN];   // pooling cross-wave reduce, 2 KB

  int r0 = blockIdx.x * BM;
  int c0 = blockIdx.y * BN;
  int t = threadIdx.x;
  int tx = t & 15;   // col group
  int ty = t >> 4;   // row group

  float acc[8][8];
#pragma unroll
  for (int i = 0; i < 8; i++)
#pragma unroll
    for (int j = 0; j < 8; j++) acc[i][j] = 0.f;

  for (int kp = 0; kp < IN_DIM; kp += BK) {
    // stage A with transpose: 128 rows x 32 k -> As[k][row]
    {
      int kq = (t & 7) << 2;  // 0,4,..,28
      int row = t >> 3;       // 0..31
#pragma unroll
      for (int it = 0; it < 4; it++) {
        int rl = row + it * 32;
        int grow = r0 + rl;
        int srow = grow < N_NODES ? grow : N_NODES - 1;  // clamp; pool guards
        float4 vv = *(const float4*)&agg[(size_t)srow * IN_DIM + kp + kq];
        As[kq + 0][rl] = vv.x;
        As[kq + 1][rl] = vv.y;
        As[kq + 2][rl] = vv.z;
        As[kq + 3][rl] = vv.w;
      }
    }
    // stage B: 32 k x 128 cols (row-major, direct)
    {
      int cc = (t & 31) << 2;  // 0..124
      int kk = t >> 5;         // 0..7
#pragma unroll
      for (int it = 0; it < 4; it++) {
        int kl = kk + it * 8;
        float4 vv = *(const float4*)&W[(size_t)(kp + kl) * HID + c0 + cc];
        *(float4*)&Bs[kl][cc] = vv;
      }
    }
    __syncthreads();

#pragma unroll 2
    for (int kk = 0; kk < BK; kk++) {
      float4 a0 = *(float4*)&As[kk][ty * 4];
      float4 a1 = *(float4*)&As[kk][64 + ty * 4];
      float4 b0 = *(float4*)&Bs[kk][tx * 4];
      float4 b1 = *(float4*)&Bs[kk][64 + tx * 4];
      float av[8] = {a0.x, a0.y, a0.z, a0.w, a1.x, a1.y, a1.z, a1.w};
      float bv[8] = {b0.x, b0.y, b0.z, b0.w, b1.x, b1.y, b1.z, b1.w};
#pragma unroll
      for (int i = 0; i < 8; i++)
#pragma unroll
        for (int j = 0; j < 8; j++) acc[i][j] += av[i] * bv[j];
    }
    __syncthreads();
  }

  // ---- epilogue: bias + relu in place ----
  float bias_v[8];
#pragma unroll
  for (int j = 0; j < 8; j++) {
    int c = c0 + ((j < 4) ? (tx * 4 + j) : (64 + tx * 4 + j - 4));
    bias_v[j] = bias[c];
  }
  int gid[8];
#pragma unroll
  for (int i = 0; i < 8; i++) {
    int r = r0 + ((i < 4) ? (ty * 4 + i) : (64 + ty * 4 + i - 4));
    gid[i] = (r < N_NODES) ? graph_ids[r] : -1;
  }
#pragma unroll
  for (int i = 0; i < 8; i++)
#pragma unroll
    for (int j = 0; j < 8; j++) acc[i][j] = fmaxf(acc[i][j] + bias_v[j], 0.f);

  // ---- fused max-pool: per-graph block reduction, then 1 atomic/col ----
  int gmin = graph_ids[r0];
  int rlast = r0 + BM - 1;
  if (rlast >= N_NODES) rlast = N_NODES - 1;
  int gmax = graph_ids[rlast];
  int w = t >> 6;  // wave id 0..3

  for (int g = gmin; g <= gmax; g++) {
    float m[8];
#pragma unroll
    for (int j = 0; j < 8; j++) m[j] = 0.f;  // relu output >= 0, so 0 is identity
#pragma unroll
    for (int i = 0; i < 8; i++) {
      if (gid[i] == g) {
#pragma unroll
        for (int j = 0; j < 8; j++) m[j] = fmaxf(m[j], acc[i][j]);
      }
    }
#pragma unroll
    for (int j = 0; j < 8; j++) {
      m[j] = fmaxf(m[j], __shfl_xor(m[j], 16, 64));
      m[j] = fmaxf(m[j], __shfl_xor(m[j], 32, 64));
    }
    if ((t & 63) < 16) {
#pragma unroll
      for (int j = 0; j < 8; j++) {
        int cl = (j < 4) ? (tx * 4 + j) : (64 + tx * 4 + j - 4);
        red[w][cl] = m[j];
      }
    }
    __syncthreads();
    if (t < BN) {
      float mm = fmaxf(fmaxf(red[0][t], red[1][t]), fmaxf(red[2][t], red[3][t]));
      atomicMax((unsigned int*)&hg[g * HID + c0 + t], __float_as_uint(mm));
    }
    __syncthreads();
  }
}

// ---------- K8: tiny classifier GEMM + log_softmax. 1 block, 64 thr ----------
__global__ void k_classify(const float* __restrict__ hg, const float* __restrict__ Wc,
                           const float* __restrict__ bc, float* __restrict__ out) {
  int g = threadIdx.x;
  if (g >= N_GRAPHS) return;
  float logits[NCLS];
#pragma unroll
  for (int c = 0; c < NCLS; c++) logits[c] = bc[c];
  for (int k = 0; k < HID; k++) {
    float h = hg[g * HID + k];
#pragma unroll
    for (int c = 0; c < NCLS; c++) logits[c] += h * Wc[k * NCLS + c];
  }
  float m = logits[0];
#pragma unroll
  for (int c = 1; c < NCLS; c++) m = fmaxf(m, logits[c]);
  float s = 0.f;
#pragma unroll
  for (int c = 0; c < NCLS; c++) s += expf(logits[c] - m);
  float lse = logf(s) + m;
#pragma unroll
  for (int c = 0; c < NCLS; c++) out[g * NCLS + c] = logits[c] - lse;
}

extern "C" void kernel_launch(void* const* d_in, const int* in_sizes, int n_in,
                              void* d_out, int out_size, void* d_ws, size_t ws_size,
                              hipStream_t stream) {
  const float* x = (const float*)d_in[0];
  const int* src = (const int*)d_in[1];
  const int* dst = (const int*)d_in[2];
  const int* graph_ids = (const int*)d_in[3];
  const float* W = (const float*)d_in[4];
  const float* b = (const float*)d_in[5];
  const float* Wc = (const float*)d_in[6];
  const float* bc = (const float*)d_in[7];
  float* out = (float*)d_out;

  // ---- workspace layout (~86 MB with xs) ----
  int* deg_out = (int*)d_ws;                  // 100000
  int* deg_in = deg_out + N_NODES;            // 100000
  float* hg = (float*)(deg_in + N_NODES);     // 64*256 = 16384
  float* norm_src = hg + N_GRAPHS * HID;      // 100000
  float* norm_dst = norm_src + N_NODES;       // 100000
  int* offs = (int*)(norm_dst + N_NODES);     // 100000
  int* cursor = offs + N_NODES;               // 100000
  int* blockSums = cursor + N_NODES;          // 128
  int* edge_src = blockSums + 128;            // 1600000
  float* agg = (float*)(edge_src + N_EDGES);  // 100000*128 f32
  __hip_bfloat162* xs = (__hip_bfloat162*)(agg + (size_t)N_NODES * IN_DIM);  // 100000*64
  size_t need = (char*)(xs + (size_t)N_NODES * (IN_DIM / 2)) - (char*)d_ws;
  bool use_bf16 = ws_size >= need;
  // degree-histogram scratch aliases agg's slot (25.6 MB < 51.2 MB; its
  // lifetime ends at k_degreduce, before agg is written by k_aggregate)
  int* deg_scratch = (int*)agg;

  // zero deg_out, deg_in, hg (contiguous prefix of ws)
  size_t zbytes = (size_t)(2 * N_NODES + N_GRAPHS * HID) * 4;
  hipMemsetAsync(d_ws, 0, zbytes, stream);

  k_deghist<<<dim3(NSLC, NREG, 2), 256, 0, stream>>>(src, dst, deg_scratch);
  k_degreduce<<<(2 * N_NODES + 255) / 256, 256, 0, stream>>>(deg_scratch, deg_in, deg_out);
  k_scan1<<<SCAN_BLOCKS, 256, 0, stream>>>(deg_in, offs, blockSums);
  k_scan2<<<1, 128, 0, stream>>>(blockSums);
  k_finalize<<<(N_NODES + 255) / 256, 256, 0, stream>>>(deg_out, deg_in, blockSums,
                                                        offs, cursor, norm_src, norm_dst);
  if (use_bf16)
    k_premul<<<(N_NODES * (IN_DIM / 2) + 255) / 256, 256, 0, stream>>>(x, norm_src, xs);
  k_scatter<<<2048, 256, 0, stream>>>(src, dst, cursor, edge_src);
  if (use_bf16)
    k_aggregate<<<N_NODES / 4, 256, 0, stream>>>(xs, edge_src, offs, deg_in,
                                                 norm_dst, agg);
  else
    k_aggregate_f32<<<N_NODES / 4, 256, 0, stream>>>(x, edge_src, offs, deg_in,
                                                     norm_src, norm_dst, agg);
  dim3 ggrid((N_NODES + BM - 1) / BM, HID / BN);
  k_gemm_pool<<<ggrid, 256, 0, stream>>>(agg, W, b, graph_ids, hg);
  k_classify<<<1, 64, 0, stream>>>(hg, Wc, bc, out);
}

// Round 12
// 383.122 us; speedup vs baseline: 11.2937x; 1.0732x over previous
//
#include <hip/hip_runtime.h>
#include <hip/hip_bf16.h>
#include <math.h>

#define N_NODES 100000
#define N_EDGES 1600000
#define N_GRAPHS 64
#define IN_DIM 128
#define HID 256
#define NCLS 16

#define SCAN_CHUNK 1024
#define SCAN_BLOCKS ((N_NODES + SCAN_CHUNK - 1) / SCAN_CHUNK)  // 98

typedef __attribute__((ext_vector_type(8))) short short8v;   // 8 bf16 (A/B frag)
typedef __attribute__((ext_vector_type(4))) float f32x4;     // C/D frag

// round-to-nearest-even f32 -> bf16 (bit pattern)
__device__ __forceinline__ unsigned short bf16_rne(float f) {
  unsigned int u = __float_as_uint(f);
  u += 0x7fffu + ((u >> 16) & 1u);
  return (unsigned short)(u >> 16);
}
__device__ __forceinline__ float bf16_to_f32(unsigned short h) {
  return __uint_as_float(((unsigned int)h) << 16);
}

// ---- K1: degree count via LDS-privatized histograms (R6) ----
// R6 post-mortem: global atomicAdd degree count = 3.2M device-scope RMWs
// executing past L2 (per-XCD L2 non-coherent) -> 99.8MB WRITE_SIZE, 124us,
// atomic-rate-bound. Fix: zero global atomics. 8 node-regions x 50KB LDS
// histograms; 32 edge-slices; plain coalesced scratch writes + tree reduce.
#define NREG 8
#define REGSZ (N_NODES / NREG)    // 12500
#define NSLC 32
#define SLICE (N_EDGES / NSLC)    // 50000

__global__ __launch_bounds__(256) void k_deghist(
    const int* __restrict__ src, const int* __restrict__ dst,
    int* __restrict__ scratch) {
  __shared__ int hist[REGSZ];  // 50 KB
  int slice = blockIdx.x, region = blockIdx.y, z = blockIdx.z;
  const int* arr = z ? src : dst;
  int t = threadIdx.x;
  for (int r = t; r < REGSZ; r += 256) hist[r] = 0;
  __syncthreads();
  int base = region * REGSZ;
  const int4* a4 = (const int4*)(arr + (size_t)slice * SLICE);
  for (int i = t; i < SLICE / 4; i += 256) {
    int4 v = a4[i];
    int d;
    d = v.x - base; if ((unsigned)d < REGSZ) atomicAdd(&hist[d], 1);
    d = v.y - base; if ((unsigned)d < REGSZ) atomicAdd(&hist[d], 1);
    d = v.z - base; if ((unsigned)d < REGSZ) atomicAdd(&hist[d], 1);
    d = v.w - base; if ((unsigned)d < REGSZ) atomicAdd(&hist[d], 1);
  }
  __syncthreads();
  int* outp = scratch + ((size_t)(z * NREG + region) * NSLC + slice) * REGSZ;
  for (int r = t; r < REGSZ; r += 256) outp[r] = hist[r];
}

__global__ void k_degreduce(const int* __restrict__ scratch,
                            int* __restrict__ deg_in, int* __restrict__ deg_out) {
  int i = blockIdx.x * blockDim.x + threadIdx.x;
  if (i >= 2 * N_NODES) return;
  int z = i / N_NODES;
  int node = i - z * N_NODES;
  int region = node / REGSZ;
  int r = node - region * REGSZ;
  const int* p = scratch + (size_t)(z * NREG + region) * NSLC * REGSZ + r;
  int s = 0;
#pragma unroll
  for (int sl = 0; sl < NSLC; sl++) s += p[(size_t)sl * REGSZ];
  if (z == 0) deg_in[node] = s; else deg_out[node] = s;
}

// ---------------- K2: per-chunk exclusive scan of deg_in ----------------
__global__ void k_scan1(const int* __restrict__ deg_in, int* __restrict__ offs,
                        int* __restrict__ blockSums) {
  __shared__ int sdata[256];
  int b = blockIdx.x, t = threadIdx.x;
  int base = b * SCAN_CHUNK + t * 4;
  int v[4];
#pragma unroll
  for (int j = 0; j < 4; j++) {
    int idx = base + j;
    v[j] = (idx < N_NODES) ? deg_in[idx] : 0;
  }
  int tsum = v[0] + v[1] + v[2] + v[3];
  sdata[t] = tsum;
  __syncthreads();
  for (int off = 1; off < 256; off <<= 1) {
    int x = sdata[t];
    int y = (t >= off) ? sdata[t - off] : 0;
    __syncthreads();
    sdata[t] = x + y;
    __syncthreads();
  }
  int run = sdata[t] - tsum;  // exclusive prefix of this thread's chunk
#pragma unroll
  for (int j = 0; j < 4; j++) {
    int idx = base + j;
    if (idx < N_NODES) offs[idx] = run;
    run += v[j];
  }
  if (t == 255) blockSums[b] = sdata[255];
}

// ---------------- K3: scan the 98 block sums (one block) ----------------
__global__ void k_scan2(int* __restrict__ blockSums) {
  __shared__ int sdata[128];
  int t = threadIdx.x;
  int v = (t < SCAN_BLOCKS) ? blockSums[t] : 0;
  sdata[t] = v;
  __syncthreads();
  for (int off = 1; off < 128; off <<= 1) {
    int x = sdata[t];
    int y = (t >= off) ? sdata[t - off] : 0;
    __syncthreads();
    sdata[t] = x + y;
    __syncthreads();
  }
  if (t < SCAN_BLOCKS) blockSums[t] = sdata[t] - v;  // exclusive
}

// ------- K4: finalize offsets, init cursors, compute D^-1/2 norms -------
__global__ void k_finalize(const int* __restrict__ deg_out, const int* __restrict__ deg_in,
                           const int* __restrict__ blockSums,
                           int* __restrict__ offs, int* __restrict__ cursor,
                           float* __restrict__ norm_src, float* __restrict__ norm_dst) {
  int i = blockIdx.x * blockDim.x + threadIdx.x;
  if (i >= N_NODES) return;
  int o = offs[i] + blockSums[i / SCAN_CHUNK];
  offs[i] = o;
  cursor[i] = o;
  norm_src[i] = rsqrtf((float)deg_out[i] + 1.0f);  // self-loop adds +1
  norm_dst[i] = rsqrtf((float)deg_in[i] + 1.0f);
}

// ------ K4b: premultiply xs = x * norm_src, stored bf16 (R4) ------
// (R6: absmax 0.0156, passes.) Halves the gathered row; folds norm_src in.
__global__ void k_premul(const float* __restrict__ x, const float* __restrict__ norm_src,
                         __hip_bfloat162* __restrict__ xs) {
  int i = blockIdx.x * blockDim.x + threadIdx.x;  // one float2 per thread
  if (i >= N_NODES * (IN_DIM / 2)) return;
  int v = i >> 6;  // IN_DIM/2 == 64 pairs per node
  float ns = norm_src[v];
  float2 a = ((const float2*)x)[i];
  __hip_bfloat162 o;
  o.x = __float2bfloat16(a.x * ns);
  o.y = __float2bfloat16(a.y * ns);
  xs[i] = o;
}

// ------ K4c: pre-transpose W to bf16 n-major Wt[n][k] (R7, for MFMA B-frags) ------
__global__ void k_prepW(const float* __restrict__ W, unsigned short* __restrict__ Wt) {
  int i = blockIdx.x * blockDim.x + threadIdx.x;
  if (i >= HID * IN_DIM) return;
  int n = i >> 7;        // 0..255
  int k = i & 127;       // 0..127
  Wt[n * IN_DIM + k] = bf16_rne(W[(size_t)k * HID + n]);
}

// ------------- K5: XCD-partitioned scatter into CSR buckets -------------
// R3 post-mortem: naive scatter = random 4B writes -> 107MB write-backs.
// Fix: 8 dst-regions (~800KB CSR window each, fits one XCD L2).
#define SC_SLICES 256
#define SC_CHUNK (N_EDGES / SC_SLICES)  // 6250
#define SC_REGION (N_NODES / 8)         // 12500
__global__ __launch_bounds__(256) void k_scatter(
    const int* __restrict__ src, const int* __restrict__ dst,
    int* __restrict__ cursor, int* __restrict__ edge_src) {
  int slice = blockIdx.x >> 3;
  int region = blockIdx.x & 7;
  int base = slice * SC_CHUNK;
  for (int i = threadIdx.x; i < SC_CHUNK; i += 256) {
    int e = base + i;
    int d = dst[e];
    if (d / SC_REGION == region) {
      int pos = atomicAdd(&cursor[d], 1);
      edge_src[pos] = src[e];
    }
  }
}

// --------- K6: pull-aggregate from bf16 xs. One wave per node ---------
__global__ __launch_bounds__(256) void k_aggregate(
    const __hip_bfloat162* __restrict__ xs, const int* __restrict__ edge_src,
    const int* __restrict__ offs, const int* __restrict__ deg_in,
    const float* __restrict__ norm_dst, float* __restrict__ agg) {
  int wave = (blockIdx.x * blockDim.x + threadIdx.x) >> 6;
  int lane = threadIdx.x & 63;
  if (wave >= N_NODES) return;
  int v = wave;
  __hip_bfloat162 a = xs[(size_t)v * 64 + lane];
  float accx = __bfloat162float(a.x), accy = __bfloat162float(a.y);
  int beg = offs[v];
  int deg = deg_in[v];
  int e = beg;
  int end8 = beg + (deg & ~7);
  for (; e < end8; e += 8) {
    int u0 = edge_src[e + 0], u1 = edge_src[e + 1];
    int u2 = edge_src[e + 2], u3 = edge_src[e + 3];
    int u4 = edge_src[e + 4], u5 = edge_src[e + 5];
    int u6 = edge_src[e + 6], u7 = edge_src[e + 7];
    __hip_bfloat162 x0 = xs[(size_t)u0 * 64 + lane];
    __hip_bfloat162 x1 = xs[(size_t)u1 * 64 + lane];
    __hip_bfloat162 x2 = xs[(size_t)u2 * 64 + lane];
    __hip_bfloat162 x3 = xs[(size_t)u3 * 64 + lane];
    __hip_bfloat162 x4 = xs[(size_t)u4 * 64 + lane];
    __hip_bfloat162 x5 = xs[(size_t)u5 * 64 + lane];
    __hip_bfloat162 x6 = xs[(size_t)u6 * 64 + lane];
    __hip_bfloat162 x7 = xs[(size_t)u7 * 64 + lane];
    accx += __bfloat162float(x0.x) + __bfloat162float(x1.x) +
            __bfloat162float(x2.x) + __bfloat162float(x3.x) +
            __bfloat162float(x4.x) + __bfloat162float(x5.x) +
            __bfloat162float(x6.x) + __bfloat162float(x7.x);
    accy += __bfloat162float(x0.y) + __bfloat162float(x1.y) +
            __bfloat162float(x2.y) + __bfloat162float(x3.y) +
            __bfloat162float(x4.y) + __bfloat162float(x5.y) +
            __bfloat162float(x6.y) + __bfloat162float(x7.y);
  }
  int end = beg + deg;
  for (; e < end; e++) {
    int u = edge_src[e];
    __hip_bfloat162 xu = xs[(size_t)u * 64 + lane];
    accx += __bfloat162float(xu.x);
    accy += __bfloat162float(xu.y);
  }
  float nd = norm_dst[v];
  float2 outv;
  outv.x = accx * nd;
  outv.y = accy * nd;
  ((float2*)(agg + (size_t)v * IN_DIM))[lane] = outv;
}

// -------- K6f: f32 fallback aggregate (used only if ws too small) --------
__global__ __launch_bounds__(256) void k_aggregate_f32(
    const float* __restrict__ x, const int* __restrict__ edge_src,
    const int* __restrict__ offs, const int* __restrict__ deg_in,
    const float* __restrict__ norm_src, const float* __restrict__ norm_dst,
    float* __restrict__ agg) {
  int wave = (blockIdx.x * blockDim.x + threadIdx.x) >> 6;
  int lane = threadIdx.x & 63;
  if (wave >= N_NODES) return;
  int v = wave;
  float2 a = ((const float2*)(x + (size_t)v * IN_DIM))[lane];
  float ns = norm_src[v];
  float accx = a.x * ns, accy = a.y * ns;
  int beg = offs[v];
  int deg = deg_in[v];
  for (int e = beg; e < beg + deg; e++) {
    int u = edge_src[e];
    float nu = norm_src[u];
    float2 xu = ((const float2*)(x + (size_t)u * IN_DIM))[lane];
    accx += xu.x * nu;
    accy += xu.y * nu;
  }
  float nd = norm_dst[v];
  float2 outv;
  outv.x = accx * nd;
  outv.y = accy * nd;
  ((float2*)(agg + (size_t)v * IN_DIM))[lane] = outv;
}

// ------ K7: MFMA bf16 GEMM (hi/lo split A) + bias + ReLU + fused pool (R7) ------
// R7 post-mortem: f32 VALU GEMM = 93us, VALUBusy 61%, floor ~42us at 157TF.
// MFMA bf16 runs the 13.1 GFLOP (2x for hi/lo) in ~2us of matrix-pipe time;
// kernel becomes a memory stream. No LDS staging: A-frags built in registers
// from coalesced-by-line agg loads (lane reads 32B of one row; all bytes
// used); B-frags read directly from pre-transposed bf16 Wt (64KB, L2-hot).
// A = Ah + Al (two bf16) keeps A at ~16 mantissa bits; only W's bf16
// rounding (~0.4% rel) adds output error (~3e-3). Layouts per m89-verified
// mapping: A row / B col = lane&15, k-chunk = (lane>>4)*8; C/D col=lane&15,
// row=(lane>>4)*4+reg. k-order consistency between A and B frags makes the
// result invariant to the hardware's internal k permutation.
#define GBM 128  // rows per block (4 waves x 32)
#define GBN 128  // cols per block (8 n-tiles)

__global__ __launch_bounds__(256, 4) void k_gemm_pool(
    const float* __restrict__ agg, const unsigned short* __restrict__ Wt,
    const float* __restrict__ bias, const int* __restrict__ graph_ids,
    float* __restrict__ hg) {
  __shared__ float red[4][GBN];  // pool cross-wave reduce, 2KB

  int r0 = blockIdx.x * GBM;
  int c0 = blockIdx.y * GBN;
  int t = threadIdx.x;
  int w = t >> 6;         // wave 0..3
  int lane = t & 63;
  int lg = lane >> 4;     // k-group 0..3 (and C/D row-group)
  int li = lane & 15;     // A row / B col / C col within tile
  int m_wave = r0 + w * 32;

  f32x4 acc[2][8];
#pragma unroll
  for (int tm = 0; tm < 2; tm++)
#pragma unroll
    for (int tn = 0; tn < 8; tn++) acc[tm][tn] = (f32x4){0.f, 0.f, 0.f, 0.f};

#pragma unroll 1
  for (int kp = 0; kp < IN_DIM; kp += 32) {
    short8v ah[2], al[2];
#pragma unroll
    for (int tm = 0; tm < 2; tm++) {
      int row = m_wave + tm * 16 + li;
      int srow = row < N_NODES ? row : N_NODES - 1;  // clamp; pool masks
      const float* p = agg + (size_t)srow * IN_DIM + kp + lg * 8;
      float4 v0 = *(const float4*)p;
      float4 v1 = *(const float4*)(p + 4);
      float fa[8] = {v0.x, v0.y, v0.z, v0.w, v1.x, v1.y, v1.z, v1.w};
#pragma unroll
      for (int j = 0; j < 8; j++) {
        unsigned short h = bf16_rne(fa[j]);
        ah[tm][j] = (short)h;
        al[tm][j] = (short)bf16_rne(fa[j] - bf16_to_f32(h));
      }
    }
#pragma unroll
    for (int tn = 0; tn < 8; tn++) {
      int ncol = c0 + tn * 16 + li;
      short8v b = *(const short8v*)(Wt + (size_t)ncol * IN_DIM + kp + lg * 8);
#pragma unroll
      for (int tm = 0; tm < 2; tm++) {
        acc[tm][tn] = __builtin_amdgcn_mfma_f32_16x16x32_bf16(al[tm], b, acc[tm][tn], 0, 0, 0);
        acc[tm][tn] = __builtin_amdgcn_mfma_f32_16x16x32_bf16(ah[tm], b, acc[tm][tn], 0, 0, 0);
      }
    }
  }

  // ---- epilogue: bias + relu ----
  float bias_v[8];
#pragma unroll
  for (int tn = 0; tn < 8; tn++) bias_v[tn] = bias[c0 + tn * 16 + li];
  int gid[8];  // 8 rows per lane: tm*4+reg -> row m_wave + tm*16 + lg*4 + reg
#pragma unroll
  for (int tm = 0; tm < 2; tm++)
#pragma unroll
    for (int reg = 0; reg < 4; reg++) {
      int r = m_wave + tm * 16 + lg * 4 + reg;
      gid[tm * 4 + reg] = (r < N_NODES) ? graph_ids[r] : -1;
    }
#pragma unroll
  for (int tm = 0; tm < 2; tm++)
#pragma unroll
    for (int tn = 0; tn < 8; tn++)
#pragma unroll
      for (int reg = 0; reg < 4; reg++)
        acc[tm][tn][reg] = fmaxf(acc[tm][tn][reg] + bias_v[tn], 0.f);

  // ---- fused max-pool: per-graph block reduction, then 1 atomic/col ----
  int gmin = graph_ids[r0];
  int rlast = r0 + GBM - 1;
  if (rlast >= N_NODES) rlast = N_NODES - 1;
  int gmax = graph_ids[rlast];

  for (int g = gmin; g <= gmax; g++) {
    float m[8];
#pragma unroll
    for (int tn = 0; tn < 8; tn++) m[tn] = 0.f;  // relu >= 0, 0 is identity
#pragma unroll
    for (int tm = 0; tm < 2; tm++)
#pragma unroll
      for (int reg = 0; reg < 4; reg++) {
        if (gid[tm * 4 + reg] == g) {
#pragma unroll
          for (int tn = 0; tn < 8; tn++) m[tn] = fmaxf(m[tn], acc[tm][tn][reg]);
        }
      }
    // reduce across the 4 lg groups (lane bits 4,5)
#pragma unroll
    for (int tn = 0; tn < 8; tn++) {
      m[tn] = fmaxf(m[tn], __shfl_xor(m[tn], 16, 64));
      m[tn] = fmaxf(m[tn], __shfl_xor(m[tn], 32, 64));
    }
    if (lane < 16) {
#pragma unroll
      for (int tn = 0; tn < 8; tn++) red[w][tn * 16 + li] = m[tn];
    }
    __syncthreads();
    if (t < GBN) {
      float mm = fmaxf(fmaxf(red[0][t], red[1][t]), fmaxf(red[2][t], red[3][t]));
      atomicMax((unsigned int*)&hg[g * HID + c0 + t], __float_as_uint(mm));
    }
    __syncthreads();
  }
}

// ---------- K8: tiny classifier GEMM + log_softmax. 1 block, 64 thr ----------
__global__ void k_classify(const float* __restrict__ hg, const float* __restrict__ Wc,
                           const float* __restrict__ bc, float* __restrict__ out) {
  int g = threadIdx.x;
  if (g >= N_GRAPHS) return;
  float logits[NCLS];
#pragma unroll
  for (int c = 0; c < NCLS; c++) logits[c] = bc[c];
  for (int k = 0; k < HID; k++) {
    float h = hg[g * HID + k];
#pragma unroll
    for (int c = 0; c < NCLS; c++) logits[c] += h * Wc[k * NCLS + c];
  }
  float m = logits[0];
#pragma unroll
  for (int c = 1; c < NCLS; c++) m = fmaxf(m, logits[c]);
  float s = 0.f;
#pragma unroll
  for (int c = 0; c < NCLS; c++) s += expf(logits[c] - m);
  float lse = logf(s) + m;
#pragma unroll
  for (int c = 0; c < NCLS; c++) out[g * NCLS + c] = logits[c] - lse;
}

extern "C" void kernel_launch(void* const* d_in, const int* in_sizes, int n_in,
                              void* d_out, int out_size, void* d_ws, size_t ws_size,
                              hipStream_t stream) {
  const float* x = (const float*)d_in[0];
  const int* src = (const int*)d_in[1];
  const int* dst = (const int*)d_in[2];
  const int* graph_ids = (const int*)d_in[3];
  const float* W = (const float*)d_in[4];
  const float* b = (const float*)d_in[5];
  const float* Wc = (const float*)d_in[6];
  const float* bc = (const float*)d_in[7];
  float* out = (float*)d_out;

  // ---- workspace layout (~86 MB with xs) ----
  int* deg_out = (int*)d_ws;                  // 100000
  int* deg_in = deg_out + N_NODES;            // 100000
  float* hg = (float*)(deg_in + N_NODES);     // 64*256 = 16384
  float* norm_src = hg + N_GRAPHS * HID;      // 100000
  float* norm_dst = norm_src + N_NODES;       // 100000
  int* offs = (int*)(norm_dst + N_NODES);     // 100000
  int* cursor = offs + N_NODES;               // 100000
  int* blockSums = cursor + N_NODES;          // 128
  int* edge_src = blockSums + 128;            // 1600000
  unsigned short* Wt = (unsigned short*)(edge_src + N_EDGES);  // 256*128 bf16, 64KB
  float* agg = (float*)(Wt + HID * IN_DIM);   // 100000*128 f32
  __hip_bfloat162* xs = (__hip_bfloat162*)(agg + (size_t)N_NODES * IN_DIM);  // 100000*64
  size_t need = (char*)(xs + (size_t)N_NODES * (IN_DIM / 2)) - (char*)d_ws;
  bool use_bf16 = ws_size >= need;
  // degree-histogram scratch aliases agg's slot (25.6 MB < 51.2 MB; its
  // lifetime ends at k_degreduce, before agg is written by k_aggregate)
  int* deg_scratch = (int*)agg;

  // zero deg_out, deg_in, hg (contiguous prefix of ws)
  size_t zbytes = (size_t)(2 * N_NODES + N_GRAPHS * HID) * 4;
  hipMemsetAsync(d_ws, 0, zbytes, stream);

  k_prepW<<<(HID * IN_DIM + 255) / 256, 256, 0, stream>>>(W, Wt);
  k_deghist<<<dim3(NSLC, NREG, 2), 256, 0, stream>>>(src, dst, deg_scratch);
  k_degreduce<<<(2 * N_NODES + 255) / 256, 256, 0, stream>>>(deg_scratch, deg_in, deg_out);
  k_scan1<<<SCAN_BLOCKS, 256, 0, stream>>>(deg_in, offs, blockSums);
  k_scan2<<<1, 128, 0, stream>>>(blockSums);
  k_finalize<<<(N_NODES + 255) / 256, 256, 0, stream>>>(deg_out, deg_in, blockSums,
                                                        offs, cursor, norm_src, norm_dst);
  if (use_bf16)
    k_premul<<<(N_NODES * (IN_DIM / 2) + 255) / 256, 256, 0, stream>>>(x, norm_src, xs);
  k_scatter<<<2048, 256, 0, stream>>>(src, dst, cursor, edge_src);
  if (use_bf16)
    k_aggregate<<<N_NODES / 4, 256, 0, stream>>>(xs, edge_src, offs, deg_in,
                                                 norm_dst, agg);
  else
    k_aggregate_f32<<<N_NODES / 4, 256, 0, stream>>>(x, edge_src, offs, deg_in,
                                                     norm_src, norm_dst, agg);
  dim3 ggrid((N_NODES + GBM - 1) / GBM, HID / GBN);
  k_gemm_pool<<<ggrid, 256, 0, stream>>>(agg, Wt, b, graph_ids, hg);
  k_classify<<<1, 64, 0, stream>>>(hg, Wc, bc, out);
}